// Round 1
// baseline (869.247 us; speedup 1.0000x reference)
//
#include <hip/hip_runtime.h>
#include <hip/hip_bf16.h>

#define NBUCK 8192
#define CAP   4096
#define TOPN  2000
#define NP2   2048
#define OUTN  1000

__device__ __forceinline__ float4 decode_box(const float4 a, const float4 d, float W, float H) {
    float aw = a.z - a.x;
    float ah = a.w - a.y;
    float ax = a.x + 0.5f * aw;
    float ay = a.y + 0.5f * ah;
    float dw = fminf(d.z, 4.135f);
    float dh = fminf(d.w, 4.135f);
    float px = d.x * aw + ax;
    float py = d.y * ah + ay;
    float pw = expf(dw) * aw;
    float ph = expf(dh) * ah;
    float4 r;
    r.x = fminf(fmaxf(px - 0.5f * pw, 0.0f), W);
    r.y = fminf(fmaxf(py - 0.5f * ph, 0.0f), H);
    r.z = fminf(fmaxf(px + 0.5f * pw, 0.0f), W);
    r.w = fminf(fmaxf(py + 0.5f * ph, 0.0f), H);
    return r;
}

__device__ __forceinline__ unsigned score_key(const float4 a, const float4 d, float W, float H, float s) {
    float4 b = decode_box(a, d, W, H);
    bool ok = ((b.z - b.x) >= 4.0f) && ((b.w - b.y) >= 4.0f);
    float ms = ok ? s : -INFINITY;
    unsigned u = __float_as_uint(ms);
    return (u & 0x80000000u) ? ~u : (u | 0x80000000u);
}

// K1: per-image histogram of top-13 key bits (LDS-accumulated)
__global__ void k_hist(const float* __restrict__ pred, const float* __restrict__ obj,
                       const float* __restrict__ anch, const int* Hp, const int* Wp,
                       unsigned* __restrict__ hist, int N) {
    __shared__ unsigned h[NBUCK];
    int t = threadIdx.x;
    for (int i = t; i < NBUCK; i += 256) h[i] = 0;
    __syncthreads();
    int b = blockIdx.y;
    float W = (float)*Wp, H = (float)*Hp;
    int base = blockIdx.x * 2048;
    for (int e = 0; e < 8; e++) {
        int n = base + e * 256 + t;
        if (n < N) {
            float4 a = ((const float4*)anch)[n];
            float4 d = ((const float4*)pred)[(size_t)b * N + n];
            float s = obj[(size_t)b * N + n];
            unsigned key = score_key(a, d, W, H, s);
            atomicAdd(&h[key >> 19], 1u);
        }
    }
    __syncthreads();
    for (int i = t; i < NBUCK; i += 256) {
        unsigned v = h[i];
        if (v) atomicAdd(&hist[b * NBUCK + i], v);
    }
}

// K2: find boundary bucket L per image (smallest L with suffix-count >= TOPN)
__global__ void k_scan(const unsigned* __restrict__ hist, unsigned* __restrict__ Lb) {
    int b = blockIdx.x;
    const unsigned* h = hist + b * NBUCK;
    __shared__ unsigned csum[256];
    int t = threadIdx.x;
    unsigned s = 0;
    for (int j = 0; j < 32; j++) s += h[t * 32 + j];
    csum[t] = s;
    __syncthreads();
    if (t == 0) {
        unsigned run = 0, before = 0;
        int tc = -1;
        for (int c = 255; c >= 0; c--) {
            if (run + csum[c] >= (unsigned)TOPN) { tc = c; before = run; break; }
            run += csum[c];
        }
        unsigned L = 0;
        if (tc >= 0) {
            unsigned r = before;
            for (int bkt = tc * 32 + 31;; bkt--) {
                r += h[bkt];
                if (r >= (unsigned)TOPN || bkt == tc * 32) { L = (unsigned)bkt; break; }
            }
        }
        Lb[b] = L;
    }
}

// K3: collect candidates (bucket >= L), recomputing keys
__global__ void k_collect(const float* __restrict__ pred, const float* __restrict__ obj,
                          const float* __restrict__ anch, const int* Hp, const int* Wp,
                          const unsigned* __restrict__ Lb, unsigned* __restrict__ count,
                          unsigned long long* __restrict__ cand, int N) {
    int b = blockIdx.y;
    int n = blockIdx.x * 256 + threadIdx.x;
    if (n >= N) return;
    float W = (float)*Wp, H = (float)*Hp;
    float4 a = ((const float4*)anch)[n];
    float4 d = ((const float4*)pred)[(size_t)b * N + n];
    float s = obj[(size_t)b * N + n];
    unsigned key = score_key(a, d, W, H, s);
    if ((key >> 19) >= Lb[b]) {
        unsigned pos = atomicAdd(&count[b], 1u);
        if (pos < CAP) cand[(size_t)b * CAP + pos] = ((unsigned long long)key << 32) | (unsigned)(~n);
    }
}

// K4: bitonic sort CAP u64 descending per image; emit order[2048] + invalid-rank bits
__global__ void __launch_bounds__(512) k_sort(const unsigned long long* __restrict__ cand,
                       const unsigned* __restrict__ count, unsigned* __restrict__ order,
                       unsigned* __restrict__ remInit) {
    __shared__ unsigned long long s[CAP];
    int b = blockIdx.x, t = threadIdx.x;
    unsigned cnt = count[b]; if (cnt > CAP) cnt = CAP;
    for (int i = t; i < CAP; i += 512) s[i] = (i < (int)cnt) ? cand[(size_t)b * CAP + i] : 0ULL;
    __syncthreads();
    for (int k = 2; k <= CAP; k <<= 1)
        for (int j = k >> 1; j > 0; j >>= 1) {
            for (int i = t; i < CAP; i += 512) {
                int l = i ^ j;
                if (l > i) {
                    unsigned long long x = s[i], y = s[l];
                    bool sw = ((i & k) == 0) ? (x < y) : (x > y);
                    if (sw) { s[i] = y; s[l] = x; }
                }
            }
            __syncthreads();
        }
    for (int r = t; r < NP2; r += 512) {
        unsigned long long v = s[r];
        unsigned key = (unsigned)(v >> 32);
        bool valid = key > 0x007FFFFFu;
        order[b * NP2 + r] = valid ? ~((unsigned)v) : 0xFFFFFFFFu;
        if (r < TOPN && !valid) atomicOr(&remInit[b * 64 + (r >> 5)], 1u << (r & 31));
    }
}

// K5: decode the selected boxes
__global__ void k_gather(const unsigned* __restrict__ order, const float* __restrict__ pred,
                         const float* __restrict__ anch, const int* Hp, const int* Wp,
                         float4* __restrict__ topbox, int N) {
    int gid = blockIdx.x * 256 + threadIdx.x;
    int b = gid >> 11, r = gid & (NP2 - 1);
    unsigned idx = order[b * NP2 + r];
    float4 out = {0.f, 0.f, 0.f, 0.f};
    if (idx != 0xFFFFFFFFu) {
        float4 a = ((const float4*)anch)[idx];
        float4 d = ((const float4*)pred)[(size_t)b * N + idx];
        out = decode_box(a, d, (float)*Wp, (float)*Hp);
    }
    topbox[(size_t)b * NP2 + r] = out;
}

// K6: suppression bitmask: mask[i][w] bit jj = (j>i) && iou(i,j)>0.7, j=w*32+jj
__global__ void k_mask(const float4* __restrict__ topbox, unsigned* __restrict__ mask) {
    __shared__ float4 bx[NP2];
    int b = blockIdx.y;
    int t = threadIdx.y * 64 + threadIdx.x;
    for (int i = t; i < NP2; i += 256) bx[i] = topbox[(size_t)b * NP2 + i];
    __syncthreads();
    int i = blockIdx.x * 4 + threadIdx.y;   // 0..1999
    int w = threadIdx.x;                    // 0..63
    float4 bi = bx[i];
    float areai = (bi.z - bi.x) * (bi.w - bi.y);
    unsigned bits = 0;
    int jbase = w * 32;
    #pragma unroll 8
    for (int jj = 0; jj < 32; jj++) {
        int j = jbase + jj;
        if (j > i) {
            float4 bj = bx[j];
            float iw = fmaxf(fminf(bi.z, bj.z) - fmaxf(bi.x, bj.x), 0.0f);
            float ih = fmaxf(fminf(bi.w, bj.w) - fmaxf(bi.y, bj.y), 0.0f);
            float inter = iw * ih;
            float areaj = (bj.z - bj.x) * (bj.w - bj.y);
            float iou = inter / (areai + areaj - inter + 1e-9f);
            if (iou > 0.7f) bits |= (1u << jj);
        }
    }
    mask[((size_t)b * NP2 + i) * 64 + w] = bits;
}

// K7: serial greedy NMS scan (1 wave/image, lane w owns 32-bit word w), then output
__global__ void k_nms(const unsigned* __restrict__ mask, const unsigned* __restrict__ remInit,
                      const float4* __restrict__ topbox, float* __restrict__ out, int B) {
    int b = blockIdx.x;
    int lane = threadIdx.x;  // 0..63
    unsigned removed = remInit[b * 64 + lane];
    if (lane == 62) removed |= 0xFFFF0000u;   // ranks 2000..2015
    if (lane == 63) removed = 0xFFFFFFFFu;    // ranks 2016..2047
    const unsigned* m = mask + (size_t)b * NP2 * 64;
    #pragma unroll 4
    for (int i = 0; i < TOPN; i++) {
        unsigned rw = (unsigned)__shfl((int)removed, i >> 5, 64);
        unsigned row = m[(size_t)i * 64 + lane];
        if (!((rw >> (i & 31)) & 1u)) removed |= row;
    }
    unsigned keep = ~removed;
    int cnt = __popc(keep);
    int ex = cnt;
    for (int off = 1; off < 64; off <<= 1) {
        int v = __shfl_up(ex, off, 64);
        if (lane >= off) ex += v;
    }
    ex -= cnt;  // exclusive prefix across lanes
    float* vout = out + (size_t)B * (OUTN * 4);
    int pos = ex;
    for (int j = 0; j < 32; j++) {
        if ((keep >> j) & 1u) {
            if (pos < OUTN) {
                float4 bxv = topbox[(size_t)b * NP2 + lane * 32 + j];
                ((float4*)out)[(size_t)b * OUTN + pos] = bxv;
                vout[(size_t)b * OUTN + pos] = 1.0f;
            }
            pos++;
        }
    }
}

extern "C" void kernel_launch(void* const* d_in, const int* in_sizes, int n_in,
                              void* d_out, int out_size, void* d_ws, size_t ws_size,
                              hipStream_t stream) {
    const float* pred = (const float*)d_in[0];
    const float* obj  = (const float*)d_in[1];
    const float* anch = (const float*)d_in[2];
    const int* Hp = (const int*)d_in[3];
    const int* Wp = (const int*)d_in[4];
    int N = in_sizes[2] / 4;           // 250000
    int B = in_sizes[1] / N;           // 8

    char* ws = (char*)d_ws;
    size_t off = 0;
    auto take = [&](size_t bytes) { void* p = ws + off; off = (off + bytes + 255) & ~(size_t)255; return p; };
    unsigned* hist              = (unsigned*)take((size_t)B * NBUCK * 4);
    unsigned* cnt               = (unsigned*)take((size_t)B * 4);
    unsigned* Lb                = (unsigned*)take((size_t)B * 4);
    unsigned long long* cand    = (unsigned long long*)take((size_t)B * CAP * 8);
    unsigned* order             = (unsigned*)take((size_t)B * NP2 * 4);
    unsigned* remInit           = (unsigned*)take((size_t)B * 64 * 4);
    float4* topbox              = (float4*)take((size_t)B * NP2 * 16);
    unsigned* mask              = (unsigned*)take((size_t)B * NP2 * 64 * 4);

    hipMemsetAsync(hist, 0, (size_t)B * NBUCK * 4, stream);
    hipMemsetAsync(cnt, 0, (size_t)B * 4, stream);
    hipMemsetAsync(remInit, 0, (size_t)B * 64 * 4, stream);
    hipMemsetAsync(d_out, 0, (size_t)out_size * 4, stream);

    k_hist   <<<dim3((N + 2047) / 2048, B), 256, 0, stream>>>(pred, obj, anch, Hp, Wp, hist, N);
    k_scan   <<<B, 256, 0, stream>>>(hist, Lb);
    k_collect<<<dim3((N + 255) / 256, B), 256, 0, stream>>>(pred, obj, anch, Hp, Wp, Lb, cnt, cand, N);
    k_sort   <<<B, 512, 0, stream>>>(cand, cnt, order, remInit);
    k_gather <<<dim3((B * NP2) / 256), 256, 0, stream>>>(order, pred, anch, Hp, Wp, topbox, N);
    k_mask   <<<dim3(TOPN / 4, B), dim3(64, 4), 0, stream>>>(topbox, mask);
    k_nms    <<<B, 64, 0, stream>>>(mask, remInit, topbox, (float*)d_out, B);
}

// Round 2
// 377.733 us; speedup vs baseline: 2.3012x; 2.3012x over previous
//
#include <hip/hip_runtime.h>
#include <hip/hip_bf16.h>

#define NBUCK 8192
#define CAP   4096
#define TOPN  2000
#define NP2   2048
#define OUTN  1000

__device__ __forceinline__ float4 decode_box(const float4 a, const float4 d, float W, float H) {
    float aw = a.z - a.x;
    float ah = a.w - a.y;
    float ax = a.x + 0.5f * aw;
    float ay = a.y + 0.5f * ah;
    float dw = fminf(d.z, 4.135f);
    float dh = fminf(d.w, 4.135f);
    float px = d.x * aw + ax;
    float py = d.y * ah + ay;
    float pw = expf(dw) * aw;
    float ph = expf(dh) * ah;
    float4 r;
    r.x = fminf(fmaxf(px - 0.5f * pw, 0.0f), W);
    r.y = fminf(fmaxf(py - 0.5f * ph, 0.0f), H);
    r.z = fminf(fmaxf(px + 0.5f * pw, 0.0f), W);
    r.w = fminf(fmaxf(py + 0.5f * ph, 0.0f), H);
    return r;
}

__device__ __forceinline__ unsigned score_key(const float4 a, const float4 d, float W, float H, float s) {
    float4 b = decode_box(a, d, W, H);
    bool ok = ((b.z - b.x) >= 4.0f) && ((b.w - b.y) >= 4.0f);
    float ms = ok ? s : -INFINITY;
    unsigned u = __float_as_uint(ms);
    return (u & 0x80000000u) ? ~u : (u | 0x80000000u);
}

// K1: per-image histogram of top-13 key bits (LDS-accumulated)
__global__ void k_hist(const float* __restrict__ pred, const float* __restrict__ obj,
                       const float* __restrict__ anch, const int* Hp, const int* Wp,
                       unsigned* __restrict__ hist, int N) {
    __shared__ unsigned h[NBUCK];
    int t = threadIdx.x;
    for (int i = t; i < NBUCK; i += 256) h[i] = 0;
    __syncthreads();
    int b = blockIdx.y;
    float W = (float)*Wp, H = (float)*Hp;
    int base = blockIdx.x * 2048;
    for (int e = 0; e < 8; e++) {
        int n = base + e * 256 + t;
        if (n < N) {
            float4 a = ((const float4*)anch)[n];
            float4 d = ((const float4*)pred)[(size_t)b * N + n];
            float s = obj[(size_t)b * N + n];
            unsigned key = score_key(a, d, W, H, s);
            atomicAdd(&h[key >> 19], 1u);
        }
    }
    __syncthreads();
    for (int i = t; i < NBUCK; i += 256) {
        unsigned v = h[i];
        if (v) atomicAdd(&hist[b * NBUCK + i], v);
    }
}

// K2: find boundary bucket L per image (smallest L with suffix-count >= TOPN)
__global__ void k_scan(const unsigned* __restrict__ hist, unsigned* __restrict__ Lb) {
    int b = blockIdx.x;
    const unsigned* h = hist + b * NBUCK;
    __shared__ unsigned csum[256];
    int t = threadIdx.x;
    unsigned s = 0;
    for (int j = 0; j < 32; j++) s += h[t * 32 + j];
    csum[t] = s;
    __syncthreads();
    if (t == 0) {
        unsigned run = 0, before = 0;
        int tc = -1;
        for (int c = 255; c >= 0; c--) {
            if (run + csum[c] >= (unsigned)TOPN) { tc = c; before = run; break; }
            run += csum[c];
        }
        unsigned L = 0;
        if (tc >= 0) {
            unsigned r = before;
            for (int bkt = tc * 32 + 31;; bkt--) {
                r += h[bkt];
                if (r >= (unsigned)TOPN || bkt == tc * 32) { L = (unsigned)bkt; break; }
            }
        }
        Lb[b] = L;
    }
}

// K3: collect candidates (bucket >= L), recomputing keys
__global__ void k_collect(const float* __restrict__ pred, const float* __restrict__ obj,
                          const float* __restrict__ anch, const int* Hp, const int* Wp,
                          const unsigned* __restrict__ Lb, unsigned* __restrict__ count,
                          unsigned long long* __restrict__ cand, int N) {
    int b = blockIdx.y;
    int n = blockIdx.x * 256 + threadIdx.x;
    if (n >= N) return;
    float W = (float)*Wp, H = (float)*Hp;
    float4 a = ((const float4*)anch)[n];
    float4 d = ((const float4*)pred)[(size_t)b * N + n];
    float s = obj[(size_t)b * N + n];
    unsigned key = score_key(a, d, W, H, s);
    if ((key >> 19) >= Lb[b]) {
        unsigned pos = atomicAdd(&count[b], 1u);
        if (pos < CAP) cand[(size_t)b * CAP + pos] = ((unsigned long long)key << 32) | (unsigned)(~n);
    }
}

// K4: bitonic sort CAP u64 descending per image; emit order[2048] + invalid-rank bits
__global__ void __launch_bounds__(1024) k_sort(const unsigned long long* __restrict__ cand,
                       const unsigned* __restrict__ count, unsigned* __restrict__ order,
                       unsigned* __restrict__ remInit) {
    __shared__ unsigned long long s[CAP];
    int b = blockIdx.x, t = threadIdx.x;
    unsigned cnt = count[b]; if (cnt > CAP) cnt = CAP;
    for (int i = t; i < CAP; i += 1024) s[i] = (i < (int)cnt) ? cand[(size_t)b * CAP + i] : 0ULL;
    __syncthreads();
    for (int k = 2; k <= CAP; k <<= 1)
        for (int j = k >> 1; j > 0; j >>= 1) {
            for (int i = t; i < CAP; i += 1024) {
                int l = i ^ j;
                if (l > i) {
                    unsigned long long x = s[i], y = s[l];
                    bool sw = ((i & k) == 0) ? (x < y) : (x > y);
                    if (sw) { s[i] = y; s[l] = x; }
                }
            }
            __syncthreads();
        }
    for (int r = t; r < NP2; r += 1024) {
        unsigned long long v = s[r];
        unsigned key = (unsigned)(v >> 32);
        bool valid = key > 0x007FFFFFu;
        order[b * NP2 + r] = valid ? ~((unsigned)v) : 0xFFFFFFFFu;
        if (r < TOPN && !valid) atomicOr(&remInit[b * 64 + (r >> 5)], 1u << (r & 31));
    }
}

// K5: decode the selected boxes
__global__ void k_gather(const unsigned* __restrict__ order, const float* __restrict__ pred,
                         const float* __restrict__ anch, const int* Hp, const int* Wp,
                         float4* __restrict__ topbox, int N) {
    int gid = blockIdx.x * 256 + threadIdx.x;
    int b = gid >> 11, r = gid & (NP2 - 1);
    unsigned idx = order[b * NP2 + r];
    float4 out = {0.f, 0.f, 0.f, 0.f};
    if (idx != 0xFFFFFFFFu) {
        float4 a = ((const float4*)anch)[idx];
        float4 d = ((const float4*)pred)[(size_t)b * N + idx];
        out = decode_box(a, d, (float)*Wp, (float)*Hp);
    }
    topbox[(size_t)b * NP2 + r] = out;
}

// K6: suppression bitmask: mask[i][w] bit jj = (j>i) && iou(i,j)>0.7, j=w*32+jj
__global__ void k_mask(const float4* __restrict__ topbox, unsigned* __restrict__ mask) {
    __shared__ float4 bx[NP2];
    int b = blockIdx.y;
    int t = threadIdx.y * 64 + threadIdx.x;
    for (int i = t; i < NP2; i += 256) bx[i] = topbox[(size_t)b * NP2 + i];
    __syncthreads();
    int i = blockIdx.x * 4 + threadIdx.y;   // 0..1999
    int w = threadIdx.x;                    // 0..63
    float4 bi = bx[i];
    float areai = (bi.z - bi.x) * (bi.w - bi.y);
    unsigned bits = 0;
    int jbase = w * 32;
    #pragma unroll 8
    for (int jj = 0; jj < 32; jj++) {
        int j = jbase + jj;
        if (j > i) {
            float4 bj = bx[j];
            float iw = fmaxf(fminf(bi.z, bj.z) - fmaxf(bi.x, bj.x), 0.0f);
            float ih = fmaxf(fminf(bi.w, bj.w) - fmaxf(bi.y, bj.y), 0.0f);
            float inter = iw * ih;
            float areaj = (bj.z - bj.x) * (bj.w - bj.y);
            float iou = inter / (areai + areaj - inter + 1e-9f);
            if (iou > 0.7f) bits |= (1u << jj);
        }
    }
    mask[((size_t)b * NP2 + i) * 64 + w] = bits;
}

// K7: chunked word-serial greedy NMS (1 wave/image), then output.
// Chunk c = ranks [32c, 32c+32). Per chunk: 1 shfl for the chunk's removal
// word, wave-uniform 32-step serial resolve using uniform intra-chunk words,
// then parallel OR-apply of alive rows. Rows double-buffer-prefetched.
__global__ void k_nms(const unsigned* __restrict__ mask, const unsigned* __restrict__ remInit,
                      const float4* __restrict__ topbox, float* __restrict__ out, int B) {
    int b = blockIdx.x;
    int lane = threadIdx.x;  // 0..63
    unsigned removed = remInit[b * 64 + lane];
    if (lane == 62) removed |= 0xFFFF0000u;   // ranks 2000..2015
    if (lane == 63) removed = 0xFFFFFFFFu;    // ranks 2016..2047
    const unsigned* m = mask + (size_t)b * NP2 * 64;

    unsigned rA[32], rB[32], iA[32], iB[32];

#define LOADC(R, I, c) do {                                                   \
        _Pragma("unroll") for (int jj = 0; jj < 32; jj++) {                   \
            R[jj] = m[(size_t)((c) * 32 + jj) * 64 + lane];                   \
            I[jj] = m[(size_t)((c) * 32 + jj) * 64 + (c)];                    \
        }                                                                     \
    } while (0)

#define RESOLVE_APPLY(R, I, c) do {                                           \
        unsigned rw = (unsigned)__shfl((int)removed, (c), 64);                \
        unsigned alive = ~rw;                                                 \
        _Pragma("unroll") for (int jj = 0; jj < 32; jj++) {                   \
            alive &= ~(((alive >> jj) & 1u) ? I[jj] : 0u);                    \
        }                                                                     \
        unsigned acc = 0u;                                                    \
        _Pragma("unroll") for (int jj = 0; jj < 32; jj++) {                   \
            acc |= (((alive >> jj) & 1u) ? R[jj] : 0u);                       \
        }                                                                     \
        removed |= acc;                                                       \
    } while (0)

    // chunks 0..62 cover ranks < 2016; ranks >= 2000 are pre-removed (never
    // alive), so their (uninitialized) rows are never applied. Chunk 63 is
    // fully pre-removed -> skipped.
    LOADC(rA, iA, 0);
    #pragma unroll 1
    for (int c = 0; c < 62; c += 2) {
        LOADC(rB, iB, c + 1);
        RESOLVE_APPLY(rA, iA, c);
        if (c + 2 < 63) LOADC(rA, iA, c + 2);
        RESOLVE_APPLY(rB, iB, c + 1);
    }
    RESOLVE_APPLY(rA, iA, 62);

#undef LOADC
#undef RESOLVE_APPLY

    unsigned keep = ~removed;
    int cnt = __popc(keep);
    int ex = cnt;
    for (int off = 1; off < 64; off <<= 1) {
        int v = __shfl_up(ex, off, 64);
        if (lane >= off) ex += v;
    }
    ex -= cnt;  // exclusive prefix across lanes
    float* vout = out + (size_t)B * (OUTN * 4);
    int pos = ex;
    for (int j = 0; j < 32; j++) {
        if ((keep >> j) & 1u) {
            if (pos < OUTN) {
                float4 bxv = topbox[(size_t)b * NP2 + lane * 32 + j];
                ((float4*)out)[(size_t)b * OUTN + pos] = bxv;
                vout[(size_t)b * OUTN + pos] = 1.0f;
            }
            pos++;
        }
    }
}

extern "C" void kernel_launch(void* const* d_in, const int* in_sizes, int n_in,
                              void* d_out, int out_size, void* d_ws, size_t ws_size,
                              hipStream_t stream) {
    const float* pred = (const float*)d_in[0];
    const float* obj  = (const float*)d_in[1];
    const float* anch = (const float*)d_in[2];
    const int* Hp = (const int*)d_in[3];
    const int* Wp = (const int*)d_in[4];
    int N = in_sizes[2] / 4;           // 250000
    int B = in_sizes[1] / N;           // 8

    char* ws = (char*)d_ws;
    size_t off = 0;
    auto take = [&](size_t bytes) { void* p = ws + off; off = (off + bytes + 255) & ~(size_t)255; return p; };
    unsigned* hist              = (unsigned*)take((size_t)B * NBUCK * 4);
    unsigned* cnt               = (unsigned*)take((size_t)B * 4);
    unsigned* Lb                = (unsigned*)take((size_t)B * 4);
    unsigned long long* cand    = (unsigned long long*)take((size_t)B * CAP * 8);
    unsigned* order             = (unsigned*)take((size_t)B * NP2 * 4);
    unsigned* remInit           = (unsigned*)take((size_t)B * 64 * 4);
    float4* topbox              = (float4*)take((size_t)B * NP2 * 16);
    unsigned* mask              = (unsigned*)take((size_t)B * NP2 * 64 * 4);

    hipMemsetAsync(hist, 0, (size_t)B * NBUCK * 4, stream);
    hipMemsetAsync(cnt, 0, (size_t)B * 4, stream);
    hipMemsetAsync(remInit, 0, (size_t)B * 64 * 4, stream);
    hipMemsetAsync(d_out, 0, (size_t)out_size * 4, stream);

    k_hist   <<<dim3((N + 2047) / 2048, B), 256, 0, stream>>>(pred, obj, anch, Hp, Wp, hist, N);
    k_scan   <<<B, 256, 0, stream>>>(hist, Lb);
    k_collect<<<dim3((N + 255) / 256, B), 256, 0, stream>>>(pred, obj, anch, Hp, Wp, Lb, cnt, cand, N);
    k_sort   <<<B, 1024, 0, stream>>>(cand, cnt, order, remInit);
    k_gather <<<dim3((B * NP2) / 256), 256, 0, stream>>>(order, pred, anch, Hp, Wp, topbox, N);
    k_mask   <<<dim3(TOPN / 4, B), dim3(64, 4), 0, stream>>>(topbox, mask);
    k_nms    <<<B, 64, 0, stream>>>(mask, remInit, topbox, (float*)d_out, B);
}

// Round 3
// 222.401 us; speedup vs baseline: 3.9085x; 1.6984x over previous
//
#include <hip/hip_runtime.h>
#include <hip/hip_bf16.h>

#define NBUCK 8192
#define P1B   32        // pass1 blocks per image
#define CAP   4096
#define TOPN  2000
#define NP2   2048
#define OUTN  1000

__device__ __forceinline__ float4 decode_box(const float4 a, const float4 d, float W, float H) {
    float aw = a.z - a.x;
    float ah = a.w - a.y;
    float ax = a.x + 0.5f * aw;
    float ay = a.y + 0.5f * ah;
    float dw = fminf(d.z, 4.135f);
    float dh = fminf(d.w, 4.135f);
    float px = d.x * aw + ax;
    float py = d.y * ah + ay;
    float pw = expf(dw) * aw;
    float ph = expf(dh) * ah;
    float4 r;
    r.x = fminf(fmaxf(px - 0.5f * pw, 0.0f), W);
    r.y = fminf(fmaxf(py - 0.5f * ph, 0.0f), H);
    r.z = fminf(fmaxf(px + 0.5f * pw, 0.0f), W);
    r.w = fminf(fmaxf(py + 0.5f * ph, 0.0f), H);
    return r;
}

__device__ __forceinline__ unsigned score_key(const float4 a, const float4 d, float W, float H, float s) {
    float4 b = decode_box(a, d, W, H);
    bool ok = ((b.z - b.x) >= 4.0f) && ((b.w - b.y) >= 4.0f);
    float ms = ok ? s : -INFINITY;
    unsigned u = __float_as_uint(ms);
    return (u & 0x80000000u) ? ~u : (u | 0x80000000u);
}

// K1: compute+store keys, per-block LDS histogram -> plain global stores (no atomics)
__global__ void __launch_bounds__(1024) k_pass1(const float* __restrict__ pred,
        const float* __restrict__ obj, const float* __restrict__ anch,
        const int* __restrict__ Hp, const int* __restrict__ Wp,
        unsigned* __restrict__ keys, unsigned* __restrict__ bhist, int N) {
    __shared__ unsigned h[NBUCK];
    int t = threadIdx.x;
    for (int i = t; i < NBUCK; i += 1024) h[i] = 0;
    __syncthreads();
    int b = blockIdx.y, g = blockIdx.x;
    int chunk = (N + P1B - 1) / P1B;
    int base = g * chunk;
    int end = base + chunk; if (end > N) end = N;
    float W = (float)*Wp, H = (float)*Hp;
    for (int n = base + t; n < end; n += 1024) {
        float4 a = ((const float4*)anch)[n];
        float4 d = ((const float4*)pred)[(size_t)b * N + n];
        float s = obj[(size_t)b * N + n];
        unsigned key = score_key(a, d, W, H, s);
        keys[(size_t)b * N + n] = key;
        atomicAdd(&h[key >> 19], 1u);
    }
    __syncthreads();
    unsigned* out = bhist + ((size_t)(b * P1B + g)) * NBUCK;
    for (int i = t; i < NBUCK; i += 1024) out[i] = h[i];
}

// K2: merge block-hists; parallel suffix-scan to find boundary bucket L per image
__global__ void k_scan(const unsigned* __restrict__ bhist, unsigned* __restrict__ Lb) {
    __shared__ unsigned h[NBUCK];
    __shared__ unsigned csum[256];
    __shared__ unsigned suf[256];
    __shared__ int tcS;
    __shared__ unsigned beforeS;
    int b = blockIdx.x, t = threadIdx.x;
    const unsigned* src = bhist + (size_t)b * P1B * NBUCK;
    // merge: thread t handles 4 consecutive buckets per step (coalesced uint4)
    for (int c = 0; c < NBUCK / 1024; c++) {
        int bkt = c * 1024 + t * 4;
        unsigned s0 = 0, s1 = 0, s2 = 0, s3 = 0;
        for (int g = 0; g < P1B; g++) {
            uint4 v = *(const uint4*)(src + (size_t)g * NBUCK + bkt);
            s0 += v.x; s1 += v.y; s2 += v.z; s3 += v.w;
        }
        h[bkt] = s0; h[bkt + 1] = s1; h[bkt + 2] = s2; h[bkt + 3] = s3;
    }
    if (t == 0) tcS = -1;
    __syncthreads();
    unsigned s = 0;
    for (int j = 0; j < 32; j++) s += h[t * 32 + j];
    csum[t] = s; suf[t] = s;
    __syncthreads();
    // Hillis-Steele suffix sum over 256 chunks
    for (int d = 1; d < 256; d <<= 1) {
        unsigned v = (t + d < 256) ? suf[t + d] : 0;
        __syncthreads();
        suf[t] += v;
        __syncthreads();
    }
    // tc = max chunk with suffix >= TOPN
    if (suf[t] >= (unsigned)TOPN && (t == 255 || suf[t + 1] < (unsigned)TOPN)) {
        tcS = t; beforeS = (t == 255) ? 0u : suf[t + 1];
    }
    __syncthreads();
    if (t == 0) {
        unsigned L = 0;
        int tc = tcS;
        if (tc >= 0) {
            unsigned r = beforeS;
            for (int bkt = tc * 32 + 31;; bkt--) {
                r += h[bkt];
                if (r >= (unsigned)TOPN || bkt == tc * 32) { L = (unsigned)bkt; break; }
            }
        }
        Lb[b] = L;
    }
}

// K3: collect candidates from precomputed keys; LDS-aggregated, 1 global atomic/block
__global__ void k_collect(const unsigned* __restrict__ keys, const unsigned* __restrict__ Lb,
                          unsigned* __restrict__ count, unsigned long long* __restrict__ cand,
                          int N) {
    __shared__ unsigned lk[1024], ln[1024];
    __shared__ unsigned lcnt, lbase;
    int b = blockIdx.y, t = threadIdx.x;
    if (t == 0) lcnt = 0;
    __syncthreads();
    unsigned L = Lb[b];
    const unsigned* kb = keys + (size_t)b * N;
    int e = blockIdx.x * 256 + t;
    int n0 = e * 4;
    if (n0 + 3 < N) {
        uint4 kv = ((const uint4*)kb)[e];
        if ((kv.x >> 19) >= L) { unsigned p = atomicAdd(&lcnt, 1u); lk[p] = kv.x; ln[p] = n0; }
        if ((kv.y >> 19) >= L) { unsigned p = atomicAdd(&lcnt, 1u); lk[p] = kv.y; ln[p] = n0 + 1; }
        if ((kv.z >> 19) >= L) { unsigned p = atomicAdd(&lcnt, 1u); lk[p] = kv.z; ln[p] = n0 + 2; }
        if ((kv.w >> 19) >= L) { unsigned p = atomicAdd(&lcnt, 1u); lk[p] = kv.w; ln[p] = n0 + 3; }
    } else {
        for (int j = 0; j < 4; j++) {
            int n = n0 + j;
            if (n < N) {
                unsigned k = kb[n];
                if ((k >> 19) >= L) { unsigned p = atomicAdd(&lcnt, 1u); lk[p] = k; ln[p] = n; }
            }
        }
    }
    __syncthreads();
    if (t == 0) lbase = atomicAdd(&count[b * 64], lcnt);
    __syncthreads();
    unsigned c = lcnt, bs = lbase;
    for (unsigned i = t; i < c; i += 256) {
        unsigned pos = bs + i;
        if (pos < CAP) cand[(size_t)b * CAP + pos] =
            ((unsigned long long)lk[i] << 32) | (unsigned)(~ln[i]);
    }
}

// K4: bitonic sort CAP u64 descending per image; emit order[2048] + invalid-rank bits
__global__ void __launch_bounds__(1024) k_sort(const unsigned long long* __restrict__ cand,
                       const unsigned* __restrict__ count, unsigned* __restrict__ order,
                       unsigned* __restrict__ remInit) {
    __shared__ unsigned long long s[CAP];
    int b = blockIdx.x, t = threadIdx.x;
    unsigned cnt = count[b * 64]; if (cnt > CAP) cnt = CAP;
    for (int i = t; i < CAP; i += 1024) s[i] = (i < (int)cnt) ? cand[(size_t)b * CAP + i] : 0ULL;
    __syncthreads();
    for (int k = 2; k <= CAP; k <<= 1)
        for (int j = k >> 1; j > 0; j >>= 1) {
            for (int i = t; i < CAP; i += 1024) {
                int l = i ^ j;
                if (l > i) {
                    unsigned long long x = s[i], y = s[l];
                    bool sw = ((i & k) == 0) ? (x < y) : (x > y);
                    if (sw) { s[i] = y; s[l] = x; }
                }
            }
            __syncthreads();
        }
    for (int r = t; r < NP2; r += 1024) {
        unsigned long long v = s[r];
        unsigned key = (unsigned)(v >> 32);
        bool valid = key > 0x007FFFFFu;
        order[b * NP2 + r] = valid ? ~((unsigned)v) : 0xFFFFFFFFu;
        if (r < TOPN && !valid) atomicOr(&remInit[b * 64 + (r >> 5)], 1u << (r & 31));
    }
}

// K5: decode the selected boxes
__global__ void k_gather(const unsigned* __restrict__ order, const float* __restrict__ pred,
                         const float* __restrict__ anch, const int* Hp, const int* Wp,
                         float4* __restrict__ topbox, int N) {
    int gid = blockIdx.x * 256 + threadIdx.x;
    int b = gid >> 11, r = gid & (NP2 - 1);
    unsigned idx = order[b * NP2 + r];
    float4 out = {0.f, 0.f, 0.f, 0.f};
    if (idx != 0xFFFFFFFFu) {
        float4 a = ((const float4*)anch)[idx];
        float4 d = ((const float4*)pred)[(size_t)b * N + idx];
        out = decode_box(a, d, (float)*Wp, (float)*Hp);
    }
    topbox[(size_t)b * NP2 + r] = out;
}

// K6: suppression bitmask: mask[i][w] bit jj = (j>i) && iou(i,j)>0.7, j=w*32+jj
__global__ void k_mask(const float4* __restrict__ topbox, unsigned* __restrict__ mask) {
    __shared__ float4 bx[NP2];
    int b = blockIdx.y;
    int t = threadIdx.y * 64 + threadIdx.x;
    for (int i = t; i < NP2; i += 256) bx[i] = topbox[(size_t)b * NP2 + i];
    __syncthreads();
    int i = blockIdx.x * 4 + threadIdx.y;   // 0..1999
    int w = threadIdx.x;                    // 0..63
    float4 bi = bx[i];
    float areai = (bi.z - bi.x) * (bi.w - bi.y);
    unsigned bits = 0;
    int jbase = w * 32;
    #pragma unroll 8
    for (int jj = 0; jj < 32; jj++) {
        int j = jbase + jj;
        if (j > i) {
            float4 bj = bx[j];
            float iw = fmaxf(fminf(bi.z, bj.z) - fmaxf(bi.x, bj.x), 0.0f);
            float ih = fmaxf(fminf(bi.w, bj.w) - fmaxf(bi.y, bj.y), 0.0f);
            float inter = iw * ih;
            float areaj = (bj.z - bj.x) * (bj.w - bj.y);
            float iou = inter / (areai + areaj - inter + 1e-9f);
            if (iou > 0.7f) bits |= (1u << jj);
        }
    }
    mask[((size_t)b * NP2 + i) * 64 + w] = bits;
}

// K7: chunked word-serial greedy NMS (1 wave/image), then output.
__global__ void k_nms(const unsigned* __restrict__ mask, const unsigned* __restrict__ remInit,
                      const float4* __restrict__ topbox, float* __restrict__ out, int B) {
    int b = blockIdx.x;
    int lane = threadIdx.x;  // 0..63
    unsigned removed = remInit[b * 64 + lane];
    if (lane == 62) removed |= 0xFFFF0000u;   // ranks 2000..2015
    if (lane == 63) removed = 0xFFFFFFFFu;    // ranks 2016..2047
    const unsigned* m = mask + (size_t)b * NP2 * 64;

    unsigned rA[32], rB[32], iA[32], iB[32];

#define LOADC(R, I, c) do {                                                   \
        _Pragma("unroll") for (int jj = 0; jj < 32; jj++) {                   \
            R[jj] = m[(size_t)((c) * 32 + jj) * 64 + lane];                   \
            I[jj] = m[(size_t)((c) * 32 + jj) * 64 + (c)];                    \
        }                                                                     \
    } while (0)

#define RESOLVE_APPLY(R, I, c) do {                                           \
        unsigned rw = (unsigned)__shfl((int)removed, (c), 64);                \
        unsigned alive = ~rw;                                                 \
        _Pragma("unroll") for (int jj = 0; jj < 32; jj++) {                   \
            alive &= ~(((alive >> jj) & 1u) ? I[jj] : 0u);                    \
        }                                                                     \
        unsigned acc = 0u;                                                    \
        _Pragma("unroll") for (int jj = 0; jj < 32; jj++) {                   \
            acc |= (((alive >> jj) & 1u) ? R[jj] : 0u);                       \
        }                                                                     \
        removed |= acc;                                                       \
    } while (0)

    LOADC(rA, iA, 0);
    #pragma unroll 1
    for (int c = 0; c < 62; c += 2) {
        LOADC(rB, iB, c + 1);
        RESOLVE_APPLY(rA, iA, c);
        if (c + 2 < 63) LOADC(rA, iA, c + 2);
        RESOLVE_APPLY(rB, iB, c + 1);
    }
    RESOLVE_APPLY(rA, iA, 62);

#undef LOADC
#undef RESOLVE_APPLY

    unsigned keep = ~removed;
    int cnt = __popc(keep);
    int ex = cnt;
    for (int off = 1; off < 64; off <<= 1) {
        int v = __shfl_up(ex, off, 64);
        if (lane >= off) ex += v;
    }
    ex -= cnt;  // exclusive prefix across lanes
    float* vout = out + (size_t)B * (OUTN * 4);
    int pos = ex;
    for (int j = 0; j < 32; j++) {
        if ((keep >> j) & 1u) {
            if (pos < OUTN) {
                float4 bxv = topbox[(size_t)b * NP2 + lane * 32 + j];
                ((float4*)out)[(size_t)b * OUTN + pos] = bxv;
                vout[(size_t)b * OUTN + pos] = 1.0f;
            }
            pos++;
        }
    }
}

extern "C" void kernel_launch(void* const* d_in, const int* in_sizes, int n_in,
                              void* d_out, int out_size, void* d_ws, size_t ws_size,
                              hipStream_t stream) {
    const float* pred = (const float*)d_in[0];
    const float* obj  = (const float*)d_in[1];
    const float* anch = (const float*)d_in[2];
    const int* Hp = (const int*)d_in[3];
    const int* Wp = (const int*)d_in[4];
    int N = in_sizes[2] / 4;           // 250000
    int B = in_sizes[1] / N;           // 8

    char* ws = (char*)d_ws;
    size_t off = 0;
    auto take = [&](size_t bytes) { void* p = ws + off; off = (off + bytes + 255) & ~(size_t)255; return p; };

    // Region A: keys (live k_pass1..k_collect), then reused for mask (k_mask..k_nms)
    size_t regA_bytes = (size_t)B * N * 4;                       // 8.0 MB
    size_t mask_bytes = (size_t)B * NP2 * 64 * 4;                // 4.2 MB (< regA)
    char* regA = (char*)take(regA_bytes > mask_bytes ? regA_bytes : mask_bytes);
    unsigned* keys = (unsigned*)regA;
    unsigned* mask = (unsigned*)regA;
    // Region B: bhist (live k_pass1..k_scan), then cand+order+topbox (k_collect..)
    size_t bhist_bytes = (size_t)B * P1B * NBUCK * 4;            // 8.4 MB
    char* regB = (char*)take(bhist_bytes);
    unsigned* bhist = (unsigned*)regB;
    unsigned long long* cand = (unsigned long long*)regB;                        // 256 KB
    unsigned* order = (unsigned*)(regB + ((size_t)B * CAP * 8 + 255 & ~(size_t)255));
    float4* topbox = (float4*)((char*)order + (((size_t)B * NP2 * 4 + 255) & ~(size_t)255));
    // Persistent small
    unsigned* cnt     = (unsigned*)take((size_t)B * 64 * 4);
    unsigned* Lb      = (unsigned*)take((size_t)B * 4);
    unsigned* remInit = (unsigned*)take((size_t)B * 64 * 4);

    hipMemsetAsync(cnt, 0, (size_t)B * 64 * 4, stream);
    hipMemsetAsync(remInit, 0, (size_t)B * 64 * 4, stream);
    hipMemsetAsync(d_out, 0, (size_t)out_size * 4, stream);

    k_pass1  <<<dim3(P1B, B), 1024, 0, stream>>>(pred, obj, anch, Hp, Wp, keys, bhist, N);
    k_scan   <<<B, 256, 0, stream>>>(bhist, Lb);
    k_collect<<<dim3((N + 1023) / 1024, B), 256, 0, stream>>>(keys, Lb, cnt, cand, N);
    k_sort   <<<B, 1024, 0, stream>>>(cand, cnt, order, remInit);
    k_gather <<<dim3((B * NP2) / 256), 256, 0, stream>>>(order, pred, anch, Hp, Wp, topbox, N);
    k_mask   <<<dim3(TOPN / 4, B), dim3(64, 4), 0, stream>>>(topbox, mask);
    k_nms    <<<B, 64, 0, stream>>>(mask, remInit, topbox, (float*)d_out, B);
}

// Round 4
// 194.085 us; speedup vs baseline: 4.4787x; 1.1459x over previous
//
#include <hip/hip_runtime.h>
#include <hip/hip_bf16.h>

#define NBUCK 8192
#define P1B   32        // pass1 blocks per image
#define CAP   4096
#define TOPN  2000
#define NP2   2048
#define OUTN  1000
#define SCH   4                 // chunks resolved per stage in k_nms
#define SROWS (SCH * 32)        // 128 rows per stage

__device__ __forceinline__ float4 decode_box(const float4 a, const float4 d, float W, float H) {
    float aw = a.z - a.x;
    float ah = a.w - a.y;
    float ax = a.x + 0.5f * aw;
    float ay = a.y + 0.5f * ah;
    float dw = fminf(d.z, 4.135f);
    float dh = fminf(d.w, 4.135f);
    float px = d.x * aw + ax;
    float py = d.y * ah + ay;
    float pw = expf(dw) * aw;
    float ph = expf(dh) * ah;
    float4 r;
    r.x = fminf(fmaxf(px - 0.5f * pw, 0.0f), W);
    r.y = fminf(fmaxf(py - 0.5f * ph, 0.0f), H);
    r.z = fminf(fmaxf(px + 0.5f * pw, 0.0f), W);
    r.w = fminf(fmaxf(py + 0.5f * ph, 0.0f), H);
    return r;
}

__device__ __forceinline__ unsigned score_key(const float4 a, const float4 d, float W, float H, float s) {
    float4 b = decode_box(a, d, W, H);
    bool ok = ((b.z - b.x) >= 4.0f) && ((b.w - b.y) >= 4.0f);
    float ms = ok ? s : -INFINITY;
    unsigned u = __float_as_uint(ms);
    return (u & 0x80000000u) ? ~u : (u | 0x80000000u);
}

// K1: compute+store keys; per-block LDS histogram merged via scattered global atomics
__global__ void __launch_bounds__(1024) k_pass1(const float* __restrict__ pred,
        const float* __restrict__ obj, const float* __restrict__ anch,
        const int* __restrict__ Hp, const int* __restrict__ Wp,
        unsigned* __restrict__ keys, unsigned* __restrict__ hist,
        unsigned* __restrict__ cnt, unsigned* __restrict__ remInit, int N) {
    __shared__ unsigned h[NBUCK];
    int t = threadIdx.x;
    int b = blockIdx.y, g = blockIdx.x;
    if (g == 0 && t < 64) { if (t == 0) cnt[b * 64] = 0; remInit[b * 64 + t] = 0; }
    for (int i = t; i < NBUCK; i += 1024) h[i] = 0;
    __syncthreads();
    int chunk = (N + P1B - 1) / P1B;
    int base = g * chunk;
    int end = base + chunk; if (end > N) end = N;
    float W = (float)*Wp, H = (float)*Hp;
    for (int n = base + t; n < end; n += 1024) {
        float4 a = ((const float4*)anch)[n];
        float4 d = ((const float4*)pred)[(size_t)b * N + n];
        float s = obj[(size_t)b * N + n];
        unsigned key = score_key(a, d, W, H, s);
        keys[(size_t)b * N + n] = key;
        atomicAdd(&h[key >> 19], 1u);
    }
    __syncthreads();
    for (int i = t; i < NBUCK; i += 1024) {
        unsigned v = h[i];
        if (v) atomicAdd(&hist[b * NBUCK + i], v);
    }
}

// K2: suffix-scan global hist to find boundary bucket L per image
__global__ void k_scan(const unsigned* __restrict__ hist, unsigned* __restrict__ Lb) {
    __shared__ unsigned h[NBUCK];
    __shared__ unsigned csum[256];
    __shared__ unsigned suf[256];
    __shared__ int tcS;
    __shared__ unsigned beforeS;
    int b = blockIdx.x, t = threadIdx.x;
    const unsigned* src = hist + (size_t)b * NBUCK;
    for (int i = t * 4; i < NBUCK; i += 1024) {
        uint4 v = *(const uint4*)(src + i);
        h[i] = v.x; h[i + 1] = v.y; h[i + 2] = v.z; h[i + 3] = v.w;
    }
    if (t == 0) tcS = -1;
    __syncthreads();
    unsigned s = 0;
    for (int j = 0; j < 32; j++) s += h[t * 32 + j];
    csum[t] = s; suf[t] = s;
    __syncthreads();
    for (int d = 1; d < 256; d <<= 1) {
        unsigned v = (t + d < 256) ? suf[t + d] : 0;
        __syncthreads();
        suf[t] += v;
        __syncthreads();
    }
    if (suf[t] >= (unsigned)TOPN && (t == 255 || suf[t + 1] < (unsigned)TOPN)) {
        tcS = t; beforeS = (t == 255) ? 0u : suf[t + 1];
    }
    __syncthreads();
    if (t == 0) {
        unsigned L = 0;
        int tc = tcS;
        if (tc >= 0) {
            unsigned r = beforeS;
            for (int bkt = tc * 32 + 31;; bkt--) {
                r += h[bkt];
                if (r >= (unsigned)TOPN || bkt == tc * 32) { L = (unsigned)bkt; break; }
            }
        }
        Lb[b] = L;
    }
}

// K3: collect candidates from precomputed keys; LDS-aggregated, 1 global atomic/block
__global__ void k_collect(const unsigned* __restrict__ keys, const unsigned* __restrict__ Lb,
                          unsigned* __restrict__ count, unsigned long long* __restrict__ cand,
                          int N) {
    __shared__ unsigned lk[1024], ln[1024];
    __shared__ unsigned lcnt, lbase;
    int b = blockIdx.y, t = threadIdx.x;
    if (t == 0) lcnt = 0;
    __syncthreads();
    unsigned L = Lb[b];
    const unsigned* kb = keys + (size_t)b * N;
    int e = blockIdx.x * 256 + t;
    int n0 = e * 4;
    if (n0 + 3 < N) {
        uint4 kv = ((const uint4*)kb)[e];
        if ((kv.x >> 19) >= L) { unsigned p = atomicAdd(&lcnt, 1u); lk[p] = kv.x; ln[p] = n0; }
        if ((kv.y >> 19) >= L) { unsigned p = atomicAdd(&lcnt, 1u); lk[p] = kv.y; ln[p] = n0 + 1; }
        if ((kv.z >> 19) >= L) { unsigned p = atomicAdd(&lcnt, 1u); lk[p] = kv.z; ln[p] = n0 + 2; }
        if ((kv.w >> 19) >= L) { unsigned p = atomicAdd(&lcnt, 1u); lk[p] = kv.w; ln[p] = n0 + 3; }
    } else {
        for (int j = 0; j < 4; j++) {
            int n = n0 + j;
            if (n < N) {
                unsigned k = kb[n];
                if ((k >> 19) >= L) { unsigned p = atomicAdd(&lcnt, 1u); lk[p] = k; ln[p] = n; }
            }
        }
    }
    __syncthreads();
    if (t == 0) lbase = atomicAdd(&count[b * 64], lcnt);
    __syncthreads();
    unsigned c = lcnt, bs = lbase;
    for (unsigned i = t; i < c; i += 256) {
        unsigned pos = bs + i;
        if (pos < CAP) cand[(size_t)b * CAP + pos] =
            ((unsigned long long)lk[i] << 32) | (unsigned)(~ln[i]);
    }
}

// K4: bitonic sort CAP u64 descending per image; fused gather/decode -> topbox
__global__ void __launch_bounds__(1024) k_sort(const unsigned long long* __restrict__ cand,
                       const unsigned* __restrict__ count,
                       const float* __restrict__ pred, const float* __restrict__ anch,
                       const int* __restrict__ Hp, const int* __restrict__ Wp,
                       float4* __restrict__ topbox, unsigned* __restrict__ remInit, int N) {
    __shared__ unsigned long long s[CAP];
    int b = blockIdx.x, t = threadIdx.x;
    unsigned cnt = count[b * 64]; if (cnt > CAP) cnt = CAP;
    for (int i = t; i < CAP; i += 1024) s[i] = (i < (int)cnt) ? cand[(size_t)b * CAP + i] : 0ULL;
    __syncthreads();
    for (int k = 2; k <= CAP; k <<= 1)
        for (int j = k >> 1; j > 0; j >>= 1) {
            for (int i = t; i < CAP; i += 1024) {
                int l = i ^ j;
                if (l > i) {
                    unsigned long long x = s[i], y = s[l];
                    bool sw = ((i & k) == 0) ? (x < y) : (x > y);
                    if (sw) { s[i] = y; s[l] = x; }
                }
            }
            __syncthreads();
        }
    float W = (float)*Wp, H = (float)*Hp;
    for (int r = t; r < NP2; r += 1024) {
        unsigned long long v = s[r];
        unsigned key = (unsigned)(v >> 32);
        bool valid = key > 0x007FFFFFu;
        float4 outb = {0.f, 0.f, 0.f, 0.f};
        if (valid) {
            unsigned idx = ~((unsigned)v);
            float4 a = ((const float4*)anch)[idx];
            float4 d = ((const float4*)pred)[(size_t)b * N + idx];
            outb = decode_box(a, d, W, H);
        }
        topbox[(size_t)b * NP2 + r] = outb;
        if (r < TOPN && !valid) atomicOr(&remInit[b * 64 + (r >> 5)], 1u << (r & 31));
    }
}

// K5: suppression bitmask: mask[i][w] bit jj = (j>i) && iou(i,j)>0.7, j=w*32+jj
__global__ void k_mask(const float4* __restrict__ topbox, unsigned* __restrict__ mask) {
    __shared__ float4 bx[NP2];
    int b = blockIdx.y;
    int t = threadIdx.y * 64 + threadIdx.x;
    for (int i = t; i < NP2; i += 256) bx[i] = topbox[(size_t)b * NP2 + i];
    __syncthreads();
    int i = blockIdx.x * 4 + threadIdx.y;   // 0..1999
    int w = threadIdx.x;                    // 0..63
    float4 bi = bx[i];
    float areai = (bi.z - bi.x) * (bi.w - bi.y);
    unsigned bits = 0;
    int jbase = w * 32;
    #pragma unroll 8
    for (int jj = 0; jj < 32; jj++) {
        int j = jbase + jj;
        if (j > i) {
            float4 bj = bx[j];
            float iw = fmaxf(fminf(bi.z, bj.z) - fmaxf(bi.x, bj.x), 0.0f);
            float ih = fmaxf(fminf(bi.w, bj.w) - fmaxf(bi.y, bj.y), 0.0f);
            float inter = iw * ih;
            float areaj = (bj.z - bj.x) * (bj.w - bj.y);
            float iou = inter / (areai + areaj - inter + 1e-9f);
            if (iou > 0.7f) bits |= (1u << jj);
        }
    }
    mask[((size_t)b * NP2 + i) * 64 + w] = bits;
}

// K6: LDS-staged chunked serial NMS. 1 block/image, 16 waves.
// Waves 1..15 stream mask rows into a 2x32KB LDS double buffer; wave 0
// resolves 4 chunks/stage with the wave-uniform serial chain on the SALU.
__global__ void __launch_bounds__(1024) k_nms(const unsigned* __restrict__ mask,
        const unsigned* __restrict__ remInit, const float4* __restrict__ topbox,
        float* __restrict__ out, int B) {
    __shared__ __align__(16) unsigned sm[2][SROWS * 64];   // 64 KB
    int b = blockIdx.x;
    int t = threadIdx.x;
    const unsigned* m = mask + (size_t)b * NP2 * 64;

    // zero this image's output slots (all threads)
    float4* ob = (float4*)out + (size_t)b * OUTN;
    for (int i = t; i < OUTN; i += 1024) ob[i] = make_float4(0.f, 0.f, 0.f, 0.f);
    float* vout = out + (size_t)B * (OUTN * 4) + (size_t)b * OUTN;
    for (int i = t; i < OUTN; i += 1024) vout[i] = 0.0f;

    // stage 0 load
    {
        const uint4* src = (const uint4*)m;
        uint4* dst = (uint4*)sm[0];
        for (int i = t; i < SROWS * 16; i += 1024) dst[i] = src[i];
    }
    __syncthreads();

    unsigned removed = 0xFFFFFFFFu;
    if (t < 64) {
        removed = remInit[b * 64 + t];
        if (t == 62) removed |= 0xFFFF0000u;   // ranks 2000..2015
        if (t == 63) removed = 0xFFFFFFFFu;    // ranks 2016..2047
    }

    const int NS = NP2 / SROWS;   // 16 stages
    for (int s = 0; s < NS; s++) {
        if (s + 1 < NS && t >= 64) {
            const uint4* src = (const uint4*)(m + (size_t)(s + 1) * SROWS * 64);
            uint4* dst = (uint4*)sm[(s + 1) & 1];
            for (int i = t - 64; i < SROWS * 16; i += 960) dst[i] = src[i];
        }
        if (t < 64) {
            const unsigned* buf = sm[s & 1];
            #pragma unroll 1
            for (int cl = 0; cl < SCH; cl++) {
                int c = s * SCH + cl;
                unsigned I[32], R[32];
                const unsigned* rowb = buf + cl * 32 * 64;
                #pragma unroll
                for (int jj = 0; jj < 32; jj++) {
                    I[jj] = rowb[jj * 64 + c];
                    R[jj] = rowb[jj * 64 + t];
                }
                unsigned rw = (unsigned)__shfl((int)removed, c, 64);
                unsigned alive = __builtin_amdgcn_readfirstlane(~rw);
                #pragma unroll
                for (int jj = 0; jj < 32; jj++) {
                    unsigned Is = __builtin_amdgcn_readfirstlane(I[jj]);
                    alive &= ~(((alive >> jj) & 1u) ? Is : 0u);
                }
                unsigned a0 = 0, a1 = 0, a2 = 0, a3 = 0;
                #pragma unroll
                for (int jj = 0; jj < 32; jj += 4) {
                    a0 |= ((alive >> jj) & 1u)       ? R[jj]     : 0u;
                    a1 |= ((alive >> (jj + 1)) & 1u) ? R[jj + 1] : 0u;
                    a2 |= ((alive >> (jj + 2)) & 1u) ? R[jj + 2] : 0u;
                    a3 |= ((alive >> (jj + 3)) & 1u) ? R[jj + 3] : 0u;
                }
                removed |= (a0 | a1) | (a2 | a3);
            }
        }
        __syncthreads();
    }

    if (t < 64) {
        unsigned keep = ~removed;
        int cnt = __popc(keep);
        int ex = cnt;
        for (int off = 1; off < 64; off <<= 1) {
            int v = __shfl_up(ex, off, 64);
            if (t >= off) ex += v;
        }
        ex -= cnt;  // exclusive prefix across lanes
        int pos = ex;
        for (int j = 0; j < 32; j++) {
            if ((keep >> j) & 1u) {
                if (pos < OUTN) {
                    float4 bxv = topbox[(size_t)b * NP2 + t * 32 + j];
                    ob[pos] = bxv;
                    vout[pos] = 1.0f;
                }
                pos++;
            }
        }
    }
}

extern "C" void kernel_launch(void* const* d_in, const int* in_sizes, int n_in,
                              void* d_out, int out_size, void* d_ws, size_t ws_size,
                              hipStream_t stream) {
    const float* pred = (const float*)d_in[0];
    const float* obj  = (const float*)d_in[1];
    const float* anch = (const float*)d_in[2];
    const int* Hp = (const int*)d_in[3];
    const int* Wp = (const int*)d_in[4];
    int N = in_sizes[2] / 4;           // 250000
    int B = in_sizes[1] / N;           // 8

    char* ws = (char*)d_ws;
    size_t off = 0;
    auto take = [&](size_t bytes) { void* p = ws + off; off = (off + bytes + 255) & ~(size_t)255; return p; };

    // Region A: keys (k_pass1..k_collect), reused as mask (k_mask..k_nms)
    size_t regA_bytes = (size_t)B * N * 4;                       // 8.0 MB
    size_t mask_bytes = (size_t)B * NP2 * 64 * 4;                // 4.2 MB (< regA)
    char* regA = (char*)take(regA_bytes > mask_bytes ? regA_bytes : mask_bytes);
    unsigned* keys = (unsigned*)regA;
    unsigned* mask = (unsigned*)regA;
    unsigned* hist           = (unsigned*)take((size_t)B * NBUCK * 4);   // 256 KB
    unsigned long long* cand = (unsigned long long*)take((size_t)B * CAP * 8);
    float4* topbox           = (float4*)take((size_t)B * NP2 * 16);
    unsigned* cnt            = (unsigned*)take((size_t)B * 64 * 4);
    unsigned* Lb             = (unsigned*)take((size_t)B * 64 * 4);
    unsigned* remInit        = (unsigned*)take((size_t)B * 64 * 4);

    hipMemsetAsync(hist, 0, (size_t)B * NBUCK * 4, stream);

    k_pass1  <<<dim3(P1B, B), 1024, 0, stream>>>(pred, obj, anch, Hp, Wp, keys, hist, cnt, remInit, N);
    k_scan   <<<B, 256, 0, stream>>>(hist, Lb);
    k_collect<<<dim3((N + 1023) / 1024, B), 256, 0, stream>>>(keys, Lb, cnt, cand, N);
    k_sort   <<<B, 1024, 0, stream>>>(cand, cnt, pred, anch, Hp, Wp, topbox, remInit, N);
    k_mask   <<<dim3(TOPN / 4, B), dim3(64, 4), 0, stream>>>(topbox, mask);
    k_nms    <<<B, 1024, 0, stream>>>(mask, remInit, topbox, (float*)d_out, B);
}

// Round 5
// 156.007 us; speedup vs baseline: 5.5719x; 1.2441x over previous
//
#include <hip/hip_runtime.h>
#include <hip/hip_bf16.h>

#define NBUCK 8192
#define P1B   32        // pass1 blocks per image
#define CAP   4096
#define TOPN  2000
#define NP2   2048
#define OUTN  1000
#define SCH   4                 // chunks resolved per stage in k_nms
#define SROWS (SCH * 32)        // 128 rows per stage

__device__ __forceinline__ float4 decode_box(const float4 a, const float4 d, float W, float H) {
    float aw = a.z - a.x;
    float ah = a.w - a.y;
    float ax = a.x + 0.5f * aw;
    float ay = a.y + 0.5f * ah;
    float dw = fminf(d.z, 4.135f);
    float dh = fminf(d.w, 4.135f);
    float px = d.x * aw + ax;
    float py = d.y * ah + ay;
    float pw = expf(dw) * aw;
    float ph = expf(dh) * ah;
    float4 r;
    r.x = fminf(fmaxf(px - 0.5f * pw, 0.0f), W);
    r.y = fminf(fmaxf(py - 0.5f * ph, 0.0f), H);
    r.z = fminf(fmaxf(px + 0.5f * pw, 0.0f), W);
    r.w = fminf(fmaxf(py + 0.5f * ph, 0.0f), H);
    return r;
}

__device__ __forceinline__ unsigned score_key(const float4 a, const float4 d, float W, float H, float s) {
    float4 b = decode_box(a, d, W, H);
    bool ok = ((b.z - b.x) >= 4.0f) && ((b.w - b.y) >= 4.0f);
    float ms = ok ? s : -INFINITY;
    unsigned u = __float_as_uint(ms);
    return (u & 0x80000000u) ? ~u : (u | 0x80000000u);
}

// K1: compute+store keys; 2 LDS sub-histograms (lane parity) to cut same-address
// atomic serialization; merged via scattered global atomics
__global__ void __launch_bounds__(1024) k_pass1(const float* __restrict__ pred,
        const float* __restrict__ obj, const float* __restrict__ anch,
        const int* __restrict__ Hp, const int* __restrict__ Wp,
        unsigned* __restrict__ keys, unsigned* __restrict__ hist,
        unsigned* __restrict__ cnt, unsigned* __restrict__ remInit, int N) {
    __shared__ unsigned h[2 * NBUCK];   // 64 KB
    int t = threadIdx.x;
    int b = blockIdx.y, g = blockIdx.x;
    if (g == 0 && t < 64) { if (t == 0) cnt[b * 64] = 0; remInit[b * 64 + t] = 0; }
    for (int i = t; i < 2 * NBUCK; i += 1024) h[i] = 0;
    __syncthreads();
    int chunk = (N + P1B - 1) / P1B;
    int base = g * chunk;
    int end = base + chunk; if (end > N) end = N;
    float W = (float)*Wp, H = (float)*Hp;
    unsigned cp = (t & 1) ? NBUCK : 0;
    for (int n = base + t; n < end; n += 1024) {
        float4 a = ((const float4*)anch)[n];
        float4 d = ((const float4*)pred)[(size_t)b * N + n];
        float s = obj[(size_t)b * N + n];
        unsigned key = score_key(a, d, W, H, s);
        keys[(size_t)b * N + n] = key;
        atomicAdd(&h[cp + (key >> 19)], 1u);
    }
    __syncthreads();
    for (int i = t; i < NBUCK; i += 1024) {
        unsigned v = h[i] + h[NBUCK + i];
        if (v) atomicAdd(&hist[b * NBUCK + i], v);
    }
}

// K2: suffix-scan global hist to find boundary bucket L per image
__global__ void k_scan(const unsigned* __restrict__ hist, unsigned* __restrict__ Lb) {
    __shared__ unsigned h[NBUCK];
    __shared__ unsigned csum[256];
    __shared__ unsigned suf[256];
    __shared__ int tcS;
    __shared__ unsigned beforeS;
    int b = blockIdx.x, t = threadIdx.x;
    const unsigned* src = hist + (size_t)b * NBUCK;
    for (int i = t * 4; i < NBUCK; i += 1024) {
        uint4 v = *(const uint4*)(src + i);
        h[i] = v.x; h[i + 1] = v.y; h[i + 2] = v.z; h[i + 3] = v.w;
    }
    if (t == 0) tcS = -1;
    __syncthreads();
    unsigned s = 0;
    for (int j = 0; j < 32; j++) s += h[t * 32 + j];
    csum[t] = s; suf[t] = s;
    __syncthreads();
    for (int d = 1; d < 256; d <<= 1) {
        unsigned v = (t + d < 256) ? suf[t + d] : 0;
        __syncthreads();
        suf[t] += v;
        __syncthreads();
    }
    if (suf[t] >= (unsigned)TOPN && (t == 255 || suf[t + 1] < (unsigned)TOPN)) {
        tcS = t; beforeS = (t == 255) ? 0u : suf[t + 1];
    }
    __syncthreads();
    if (t == 0) {
        unsigned L = 0;
        int tc = tcS;
        if (tc >= 0) {
            unsigned r = beforeS;
            for (int bkt = tc * 32 + 31;; bkt--) {
                r += h[bkt];
                if (r >= (unsigned)TOPN || bkt == tc * 32) { L = (unsigned)bkt; break; }
            }
        }
        Lb[b] = L;
    }
}

// K3: collect candidates from precomputed keys; LDS-aggregated, 1 global atomic/block
__global__ void k_collect(const unsigned* __restrict__ keys, const unsigned* __restrict__ Lb,
                          unsigned* __restrict__ count, unsigned long long* __restrict__ cand,
                          int N) {
    __shared__ unsigned lk[1024], ln[1024];
    __shared__ unsigned lcnt, lbase;
    int b = blockIdx.y, t = threadIdx.x;
    if (t == 0) lcnt = 0;
    __syncthreads();
    unsigned L = Lb[b];
    const unsigned* kb = keys + (size_t)b * N;
    int e = blockIdx.x * 256 + t;
    int n0 = e * 4;
    if (n0 + 3 < N) {
        uint4 kv = ((const uint4*)kb)[e];
        if ((kv.x >> 19) >= L) { unsigned p = atomicAdd(&lcnt, 1u); lk[p] = kv.x; ln[p] = n0; }
        if ((kv.y >> 19) >= L) { unsigned p = atomicAdd(&lcnt, 1u); lk[p] = kv.y; ln[p] = n0 + 1; }
        if ((kv.z >> 19) >= L) { unsigned p = atomicAdd(&lcnt, 1u); lk[p] = kv.z; ln[p] = n0 + 2; }
        if ((kv.w >> 19) >= L) { unsigned p = atomicAdd(&lcnt, 1u); lk[p] = kv.w; ln[p] = n0 + 3; }
    } else {
        for (int j = 0; j < 4; j++) {
            int n = n0 + j;
            if (n < N) {
                unsigned k = kb[n];
                if ((k >> 19) >= L) { unsigned p = atomicAdd(&lcnt, 1u); lk[p] = k; ln[p] = n; }
            }
        }
    }
    __syncthreads();
    if (t == 0) lbase = atomicAdd(&count[b * 64], lcnt);
    __syncthreads();
    unsigned c = lcnt, bs = lbase;
    for (unsigned i = t; i < c; i += 256) {
        unsigned pos = bs + i;
        if (pos < CAP) cand[(size_t)b * CAP + pos] =
            ((unsigned long long)lk[i] << 32) | (unsigned)(~ln[i]);
    }
}

// Register compare-exchange for one shuffle pass
#define REGX(e, p, d, lo)  ((lo) == (d) ? ((e) >= (p) ? (e) : (p)) : ((e) >= (p) ? (p) : (e)))

// K4a: bitonic sort of 512-entry chunks (8/image), direction alternating by chunk
__global__ void __launch_bounds__(256) k_sort1(unsigned long long* __restrict__ cand,
        const unsigned* __restrict__ count) {
    __shared__ unsigned long long s[512];
    int b = blockIdx.x >> 3, g = blockIdx.x & 7;
    int t = threadIdx.x;
    unsigned cnt = count[b * 64]; if (cnt > CAP) cnt = CAP;
    unsigned long long* cb = cand + (size_t)b * CAP + g * 512;
    int g0 = g * 512 + t, g1 = g * 512 + t + 256;
    unsigned long long e0 = (g0 < (int)cnt) ? cb[t] : 0ULL;
    unsigned long long e1 = (g1 < (int)cnt) ? cb[t + 256] : 0ULL;

    // stages k=2..64: pure-register shuffle passes
    #pragma unroll
    for (int k = 2; k <= 64; k <<= 1) {
        bool d0 = ((g0 & k) == 0);
        bool d1 = ((g1 & k) == 0);
        #pragma unroll
        for (int j = k >> 1; j >= 1; j >>= 1) {
            bool lo = ((t & j) == 0);
            unsigned long long p0 = __shfl_xor(e0, j, 64);
            unsigned long long p1 = __shfl_xor(e1, j, 64);
            e0 = REGX(e0, p0, d0, lo);
            e1 = REGX(e1, p1, d1, lo);
        }
    }
    // stages 128..512: LDS passes for j>=64, register passes for j<=32
    for (int k = 128; k <= 512; k <<= 1) {
        s[t] = e0; s[t + 256] = e1;
        __syncthreads();
        for (int j = k >> 1; j >= 64; j >>= 1) {
            int i = ((t & ~(j - 1)) << 1) | (t & (j - 1));
            int l = i + j;
            bool desc = (((g * 512 + i) & k) == 0);
            unsigned long long x = s[i], y = s[l];
            if (desc ? (x < y) : (x > y)) { s[i] = y; s[l] = x; }
            __syncthreads();
        }
        e0 = s[t]; e1 = s[t + 256];
        bool d0 = ((g0 & k) == 0);
        bool d1 = ((g1 & k) == 0);
        #pragma unroll
        for (int j = 32; j >= 1; j >>= 1) {
            bool lo = ((t & j) == 0);
            unsigned long long p0 = __shfl_xor(e0, j, 64);
            unsigned long long p1 = __shfl_xor(e1, j, 64);
            e0 = REGX(e0, p0, d0, lo);
            e1 = REGX(e1, p1, d1, lo);
        }
    }
    cb[t] = e0; cb[t + 256] = e1;
}

// K4b: merge stages k=1024..4096; final ranks 0..2047 end in registers ->
// fused decode/gather + remInit
__global__ void __launch_bounds__(1024) k_sort2(const unsigned long long* __restrict__ cand,
        const float* __restrict__ pred, const float* __restrict__ anch,
        const int* __restrict__ Hp, const int* __restrict__ Wp,
        float4* __restrict__ topbox, unsigned* __restrict__ remInit, int N) {
    __shared__ unsigned long long s[CAP];
    int b = blockIdx.x, t = threadIdx.x;
    const unsigned long long* cb = cand + (size_t)b * CAP;
    unsigned long long e0 = cb[t], e1 = cb[t + 1024], e2 = cb[t + 2048], e3 = cb[t + 3072];
    for (int k = 1024; k <= 4096; k <<= 1) {
        s[t] = e0; s[t + 1024] = e1; s[t + 2048] = e2; s[t + 3072] = e3;
        __syncthreads();
        for (int j = k >> 1; j >= 64; j >>= 1) {
            #pragma unroll
            for (int cc = 0; cc < 2; cc++) {
                int c = t + cc * 1024;
                int i = ((c & ~(j - 1)) << 1) | (c & (j - 1));
                int l = i + j;
                bool desc = ((i & k) == 0);
                unsigned long long x = s[i], y = s[l];
                if (desc ? (x < y) : (x > y)) { s[i] = y; s[l] = x; }
            }
            __syncthreads();
        }
        e0 = s[t]; e1 = s[t + 1024]; e2 = s[t + 2048]; e3 = s[t + 3072];
        bool d0 = ((t & k) == 0);
        bool d1 = (((t + 1024) & k) == 0);
        bool d2 = (((t + 2048) & k) == 0);
        bool d3 = (((t + 3072) & k) == 0);
        #pragma unroll
        for (int j = 32; j >= 1; j >>= 1) {
            bool lo = ((t & j) == 0);
            unsigned long long p0 = __shfl_xor(e0, j, 64);
            unsigned long long p1 = __shfl_xor(e1, j, 64);
            unsigned long long p2 = __shfl_xor(e2, j, 64);
            unsigned long long p3 = __shfl_xor(e3, j, 64);
            e0 = REGX(e0, p0, d0, lo);
            e1 = REGX(e1, p1, d1, lo);
            e2 = REGX(e2, p2, d2, lo);
            e3 = REGX(e3, p3, d3, lo);
        }
    }
    // e0 = rank t, e1 = rank t+1024; e2/e3 (ranks >= 2048) discarded
    float W = (float)*Wp, H = (float)*Hp;
    #pragma unroll
    for (int m = 0; m < 2; m++) {
        unsigned long long v = m ? e1 : e0;
        int r = t + m * 1024;
        unsigned key = (unsigned)(v >> 32);
        bool valid = key > 0x007FFFFFu;
        float4 outb = {0.f, 0.f, 0.f, 0.f};
        if (valid) {
            unsigned idx = ~((unsigned)v);
            float4 a = ((const float4*)anch)[idx];
            float4 d = ((const float4*)pred)[(size_t)b * N + idx];
            outb = decode_box(a, d, W, H);
        }
        topbox[(size_t)b * NP2 + r] = outb;
        if (r < TOPN && !valid) atomicOr(&remInit[b * 64 + (r >> 5)], 1u << (r & 31));
    }
}

// K5: suppression bitmask: mask[i][w] bit jj = (j>i) && iou(i,j)>0.7, j=w*32+jj
__global__ void k_mask(const float4* __restrict__ topbox, unsigned* __restrict__ mask) {
    __shared__ float4 bx[NP2];
    int b = blockIdx.y;
    int t = threadIdx.y * 64 + threadIdx.x;
    for (int i = t; i < NP2; i += 256) bx[i] = topbox[(size_t)b * NP2 + i];
    __syncthreads();
    int i = blockIdx.x * 4 + threadIdx.y;   // 0..1999
    int w = threadIdx.x;                    // 0..63
    float4 bi = bx[i];
    float areai = (bi.z - bi.x) * (bi.w - bi.y);
    unsigned bits = 0;
    int jbase = w * 32;
    #pragma unroll 8
    for (int jj = 0; jj < 32; jj++) {
        int j = jbase + jj;
        if (j > i) {
            float4 bj = bx[j];
            float iw = fmaxf(fminf(bi.z, bj.z) - fmaxf(bi.x, bj.x), 0.0f);
            float ih = fmaxf(fminf(bi.w, bj.w) - fmaxf(bi.y, bj.y), 0.0f);
            float inter = iw * ih;
            float areaj = (bj.z - bj.x) * (bj.w - bj.y);
            float iou = inter / (areai + areaj - inter + 1e-9f);
            if (iou > 0.7f) bits |= (1u << jj);
        }
    }
    mask[((size_t)b * NP2 + i) * 64 + w] = bits;
}

// K6: LDS-staged chunked serial NMS. 1 block/image, 16 waves.
__global__ void __launch_bounds__(1024) k_nms(const unsigned* __restrict__ mask,
        const unsigned* __restrict__ remInit, const float4* __restrict__ topbox,
        float* __restrict__ out, int B) {
    __shared__ __align__(16) unsigned sm[2][SROWS * 64];   // 64 KB
    int b = blockIdx.x;
    int t = threadIdx.x;
    const unsigned* m = mask + (size_t)b * NP2 * 64;

    float4* ob = (float4*)out + (size_t)b * OUTN;
    for (int i = t; i < OUTN; i += 1024) ob[i] = make_float4(0.f, 0.f, 0.f, 0.f);
    float* vout = out + (size_t)B * (OUTN * 4) + (size_t)b * OUTN;
    for (int i = t; i < OUTN; i += 1024) vout[i] = 0.0f;

    {
        const uint4* src = (const uint4*)m;
        uint4* dst = (uint4*)sm[0];
        for (int i = t; i < SROWS * 16; i += 1024) dst[i] = src[i];
    }
    __syncthreads();

    unsigned removed = 0xFFFFFFFFu;
    if (t < 64) {
        removed = remInit[b * 64 + t];
        if (t == 62) removed |= 0xFFFF0000u;   // ranks 2000..2015
        if (t == 63) removed = 0xFFFFFFFFu;    // ranks 2016..2047
    }

    const int NS = NP2 / SROWS;   // 16 stages
    for (int s = 0; s < NS; s++) {
        if (s + 1 < NS && t >= 64) {
            const uint4* src = (const uint4*)(m + (size_t)(s + 1) * SROWS * 64);
            uint4* dst = (uint4*)sm[(s + 1) & 1];
            for (int i = t - 64; i < SROWS * 16; i += 960) dst[i] = src[i];
        }
        if (t < 64) {
            const unsigned* buf = sm[s & 1];
            #pragma unroll 1
            for (int cl = 0; cl < SCH; cl++) {
                int c = s * SCH + cl;
                unsigned I[32], R[32];
                const unsigned* rowb = buf + cl * 32 * 64;
                #pragma unroll
                for (int jj = 0; jj < 32; jj++) {
                    I[jj] = rowb[jj * 64 + c];
                    R[jj] = rowb[jj * 64 + t];
                }
                unsigned rw = (unsigned)__shfl((int)removed, c, 64);
                unsigned alive = __builtin_amdgcn_readfirstlane(~rw);
                #pragma unroll
                for (int jj = 0; jj < 32; jj++) {
                    unsigned Is = __builtin_amdgcn_readfirstlane(I[jj]);
                    alive &= ~(((alive >> jj) & 1u) ? Is : 0u);
                }
                unsigned a0 = 0, a1 = 0, a2 = 0, a3 = 0;
                #pragma unroll
                for (int jj = 0; jj < 32; jj += 4) {
                    a0 |= ((alive >> jj) & 1u)       ? R[jj]     : 0u;
                    a1 |= ((alive >> (jj + 1)) & 1u) ? R[jj + 1] : 0u;
                    a2 |= ((alive >> (jj + 2)) & 1u) ? R[jj + 2] : 0u;
                    a3 |= ((alive >> (jj + 3)) & 1u) ? R[jj + 3] : 0u;
                }
                removed |= (a0 | a1) | (a2 | a3);
            }
        }
        __syncthreads();
    }

    if (t < 64) {
        unsigned keep = ~removed;
        int cnt = __popc(keep);
        int ex = cnt;
        for (int off = 1; off < 64; off <<= 1) {
            int v = __shfl_up(ex, off, 64);
            if (t >= off) ex += v;
        }
        ex -= cnt;
        int pos = ex;
        for (int j = 0; j < 32; j++) {
            if ((keep >> j) & 1u) {
                if (pos < OUTN) {
                    float4 bxv = topbox[(size_t)b * NP2 + t * 32 + j];
                    ob[pos] = bxv;
                    vout[pos] = 1.0f;
                }
                pos++;
            }
        }
    }
}

extern "C" void kernel_launch(void* const* d_in, const int* in_sizes, int n_in,
                              void* d_out, int out_size, void* d_ws, size_t ws_size,
                              hipStream_t stream) {
    const float* pred = (const float*)d_in[0];
    const float* obj  = (const float*)d_in[1];
    const float* anch = (const float*)d_in[2];
    const int* Hp = (const int*)d_in[3];
    const int* Wp = (const int*)d_in[4];
    int N = in_sizes[2] / 4;           // 250000
    int B = in_sizes[1] / N;           // 8

    char* ws = (char*)d_ws;
    size_t off = 0;
    auto take = [&](size_t bytes) { void* p = ws + off; off = (off + bytes + 255) & ~(size_t)255; return p; };

    // Region A: keys (k_pass1..k_collect), reused as mask (k_mask..k_nms)
    size_t regA_bytes = (size_t)B * N * 4;                       // 8.0 MB
    size_t mask_bytes = (size_t)B * NP2 * 64 * 4;                // 4.2 MB (< regA)
    char* regA = (char*)take(regA_bytes > mask_bytes ? regA_bytes : mask_bytes);
    unsigned* keys = (unsigned*)regA;
    unsigned* mask = (unsigned*)regA;
    unsigned* hist           = (unsigned*)take((size_t)B * NBUCK * 4);   // 256 KB
    unsigned long long* cand = (unsigned long long*)take((size_t)B * CAP * 8);
    float4* topbox           = (float4*)take((size_t)B * NP2 * 16);
    unsigned* cnt            = (unsigned*)take((size_t)B * 64 * 4);
    unsigned* Lb             = (unsigned*)take((size_t)B * 64 * 4);
    unsigned* remInit        = (unsigned*)take((size_t)B * 64 * 4);

    hipMemsetAsync(hist, 0, (size_t)B * NBUCK * 4, stream);

    k_pass1  <<<dim3(P1B, B), 1024, 0, stream>>>(pred, obj, anch, Hp, Wp, keys, hist, cnt, remInit, N);
    k_scan   <<<B, 256, 0, stream>>>(hist, Lb);
    k_collect<<<dim3((N + 1023) / 1024, B), 256, 0, stream>>>(keys, Lb, cnt, cand, N);
    k_sort1  <<<B * 8, 256, 0, stream>>>(cand, cnt);
    k_sort2  <<<B, 1024, 0, stream>>>(cand, pred, anch, Hp, Wp, topbox, remInit, N);
    k_mask   <<<dim3(TOPN / 4, B), dim3(64, 4), 0, stream>>>(topbox, mask);
    k_nms    <<<B, 1024, 0, stream>>>(mask, remInit, topbox, (float*)d_out, B);
}

// Round 6
// 154.791 us; speedup vs baseline: 5.6156x; 1.0079x over previous
//
#include <hip/hip_runtime.h>
#include <hip/hip_bf16.h>

#define NBUCK 8192
#define P1B   32        // pass1 blocks per image
#define CAP   4096
#define TOPN  2000
#define NP2   2048
#define OUTN  1000
#define SCH   4                 // chunks resolved per stage in k_nms
#define SROWS (SCH * 32)        // 128 rows per stage

__device__ __forceinline__ float4 decode_box(const float4 a, const float4 d, float W, float H) {
    float aw = a.z - a.x;
    float ah = a.w - a.y;
    float ax = a.x + 0.5f * aw;
    float ay = a.y + 0.5f * ah;
    float dw = fminf(d.z, 4.135f);
    float dh = fminf(d.w, 4.135f);
    float px = d.x * aw + ax;
    float py = d.y * ah + ay;
    float pw = expf(dw) * aw;
    float ph = expf(dh) * ah;
    float4 r;
    r.x = fminf(fmaxf(px - 0.5f * pw, 0.0f), W);
    r.y = fminf(fmaxf(py - 0.5f * ph, 0.0f), H);
    r.z = fminf(fmaxf(px + 0.5f * pw, 0.0f), W);
    r.w = fminf(fmaxf(py + 0.5f * ph, 0.0f), H);
    return r;
}

__device__ __forceinline__ unsigned score_key(const float4 a, const float4 d, float W, float H, float s) {
    float4 b = decode_box(a, d, W, H);
    bool ok = ((b.z - b.x) >= 4.0f) && ((b.w - b.y) >= 4.0f);
    float ms = ok ? s : -INFINITY;
    unsigned u = __float_as_uint(ms);
    return (u & 0x80000000u) ? ~u : (u | 0x80000000u);
}

// K1: compute+store keys; 2 LDS sub-histograms (lane parity); merged via global atomics
__global__ void __launch_bounds__(1024) k_pass1(const float* __restrict__ pred,
        const float* __restrict__ obj, const float* __restrict__ anch,
        const int* __restrict__ Hp, const int* __restrict__ Wp,
        unsigned* __restrict__ keys, unsigned* __restrict__ hist,
        unsigned* __restrict__ cnt, unsigned* __restrict__ remInit, int N) {
    __shared__ unsigned h[2 * NBUCK];   // 64 KB
    int t = threadIdx.x;
    int b = blockIdx.y, g = blockIdx.x;
    if (g == 0 && t < 64) { if (t == 0) cnt[b * 64] = 0; remInit[b * 64 + t] = 0; }
    for (int i = t; i < 2 * NBUCK; i += 1024) h[i] = 0;
    __syncthreads();
    int chunk = (N + P1B - 1) / P1B;
    int base = g * chunk;
    int end = base + chunk; if (end > N) end = N;
    float W = (float)*Wp, H = (float)*Hp;
    unsigned cp = (t & 1) ? NBUCK : 0;
    for (int n = base + t; n < end; n += 1024) {
        float4 a = ((const float4*)anch)[n];
        float4 d = ((const float4*)pred)[(size_t)b * N + n];
        float s = obj[(size_t)b * N + n];
        unsigned key = score_key(a, d, W, H, s);
        keys[(size_t)b * N + n] = key;
        atomicAdd(&h[cp + (key >> 19)], 1u);
    }
    __syncthreads();
    for (int i = t; i < NBUCK; i += 1024) {
        unsigned v = h[i] + h[NBUCK + i];
        if (v) atomicAdd(&hist[b * NBUCK + i], v);
    }
}

// K2: suffix-scan global hist to find boundary bucket L per image
__global__ void k_scan(const unsigned* __restrict__ hist, unsigned* __restrict__ Lb) {
    __shared__ unsigned h[NBUCK];
    __shared__ unsigned csum[256];
    __shared__ unsigned suf[256];
    __shared__ int tcS;
    __shared__ unsigned beforeS;
    int b = blockIdx.x, t = threadIdx.x;
    const unsigned* src = hist + (size_t)b * NBUCK;
    for (int i = t * 4; i < NBUCK; i += 1024) {
        uint4 v = *(const uint4*)(src + i);
        h[i] = v.x; h[i + 1] = v.y; h[i + 2] = v.z; h[i + 3] = v.w;
    }
    if (t == 0) tcS = -1;
    __syncthreads();
    unsigned s = 0;
    for (int j = 0; j < 32; j++) s += h[t * 32 + j];
    csum[t] = s; suf[t] = s;
    __syncthreads();
    for (int d = 1; d < 256; d <<= 1) {
        unsigned v = (t + d < 256) ? suf[t + d] : 0;
        __syncthreads();
        suf[t] += v;
        __syncthreads();
    }
    if (suf[t] >= (unsigned)TOPN && (t == 255 || suf[t + 1] < (unsigned)TOPN)) {
        tcS = t; beforeS = (t == 255) ? 0u : suf[t + 1];
    }
    __syncthreads();
    if (t == 0) {
        unsigned L = 0;
        int tc = tcS;
        if (tc >= 0) {
            unsigned r = beforeS;
            for (int bkt = tc * 32 + 31;; bkt--) {
                r += h[bkt];
                if (r >= (unsigned)TOPN || bkt == tc * 32) { L = (unsigned)bkt; break; }
            }
        }
        Lb[b] = L;
    }
}

// K3: collect candidates from precomputed keys; LDS-aggregated, 1 global atomic/block
__global__ void k_collect(const unsigned* __restrict__ keys, const unsigned* __restrict__ Lb,
                          unsigned* __restrict__ count, unsigned long long* __restrict__ cand,
                          int N) {
    __shared__ unsigned lk[1024], ln[1024];
    __shared__ unsigned lcnt, lbase;
    int b = blockIdx.y, t = threadIdx.x;
    if (t == 0) lcnt = 0;
    __syncthreads();
    unsigned L = Lb[b];
    const unsigned* kb = keys + (size_t)b * N;
    int e = blockIdx.x * 256 + t;
    int n0 = e * 4;
    if (n0 + 3 < N) {
        uint4 kv = ((const uint4*)kb)[e];
        if ((kv.x >> 19) >= L) { unsigned p = atomicAdd(&lcnt, 1u); lk[p] = kv.x; ln[p] = n0; }
        if ((kv.y >> 19) >= L) { unsigned p = atomicAdd(&lcnt, 1u); lk[p] = kv.y; ln[p] = n0 + 1; }
        if ((kv.z >> 19) >= L) { unsigned p = atomicAdd(&lcnt, 1u); lk[p] = kv.z; ln[p] = n0 + 2; }
        if ((kv.w >> 19) >= L) { unsigned p = atomicAdd(&lcnt, 1u); lk[p] = kv.w; ln[p] = n0 + 3; }
    } else {
        for (int j = 0; j < 4; j++) {
            int n = n0 + j;
            if (n < N) {
                unsigned k = kb[n];
                if ((k >> 19) >= L) { unsigned p = atomicAdd(&lcnt, 1u); lk[p] = k; ln[p] = n; }
            }
        }
    }
    __syncthreads();
    if (t == 0) lbase = atomicAdd(&count[b * 64], lcnt);
    __syncthreads();
    unsigned c = lcnt, bs = lbase;
    for (unsigned i = t; i < c; i += 256) {
        unsigned pos = bs + i;
        if (pos < CAP) cand[(size_t)b * CAP + pos] =
            ((unsigned long long)lk[i] << 32) | (unsigned)(~ln[i]);
    }
}

// Register compare-exchange for one shuffle pass
#define REGX(e, p, d, lo)  ((lo) == (d) ? ((e) >= (p) ? (e) : (p)) : ((e) >= (p) ? (p) : (e)))

// K4a: bitonic sort of 512-entry chunks (8/image), direction alternating by chunk
__global__ void __launch_bounds__(256) k_sort1(unsigned long long* __restrict__ cand,
        const unsigned* __restrict__ count) {
    __shared__ unsigned long long s[512];
    int b = blockIdx.x >> 3, g = blockIdx.x & 7;
    int t = threadIdx.x;
    unsigned cnt = count[b * 64]; if (cnt > CAP) cnt = CAP;
    unsigned long long* cb = cand + (size_t)b * CAP + g * 512;
    int g0 = g * 512 + t, g1 = g * 512 + t + 256;
    unsigned long long e0 = (g0 < (int)cnt) ? cb[t] : 0ULL;
    unsigned long long e1 = (g1 < (int)cnt) ? cb[t + 256] : 0ULL;

    #pragma unroll
    for (int k = 2; k <= 64; k <<= 1) {
        bool d0 = ((g0 & k) == 0);
        bool d1 = ((g1 & k) == 0);
        #pragma unroll
        for (int j = k >> 1; j >= 1; j >>= 1) {
            bool lo = ((t & j) == 0);
            unsigned long long p0 = __shfl_xor(e0, j, 64);
            unsigned long long p1 = __shfl_xor(e1, j, 64);
            e0 = REGX(e0, p0, d0, lo);
            e1 = REGX(e1, p1, d1, lo);
        }
    }
    for (int k = 128; k <= 512; k <<= 1) {
        s[t] = e0; s[t + 256] = e1;
        __syncthreads();
        for (int j = k >> 1; j >= 64; j >>= 1) {
            int i = ((t & ~(j - 1)) << 1) | (t & (j - 1));
            int l = i + j;
            bool desc = (((g * 512 + i) & k) == 0);
            unsigned long long x = s[i], y = s[l];
            if (desc ? (x < y) : (x > y)) { s[i] = y; s[l] = x; }
            __syncthreads();
        }
        e0 = s[t]; e1 = s[t + 256];
        bool d0 = ((g0 & k) == 0);
        bool d1 = ((g1 & k) == 0);
        #pragma unroll
        for (int j = 32; j >= 1; j >>= 1) {
            bool lo = ((t & j) == 0);
            unsigned long long p0 = __shfl_xor(e0, j, 64);
            unsigned long long p1 = __shfl_xor(e1, j, 64);
            e0 = REGX(e0, p0, d0, lo);
            e1 = REGX(e1, p1, d1, lo);
        }
    }
    cb[t] = e0; cb[t + 256] = e1;
}

// K4b: merge stages k=1024..4096; fused decode/gather + remInit
__global__ void __launch_bounds__(1024) k_sort2(const unsigned long long* __restrict__ cand,
        const float* __restrict__ pred, const float* __restrict__ anch,
        const int* __restrict__ Hp, const int* __restrict__ Wp,
        float4* __restrict__ topbox, unsigned* __restrict__ remInit, int N) {
    __shared__ unsigned long long s[CAP];
    int b = blockIdx.x, t = threadIdx.x;
    const unsigned long long* cb = cand + (size_t)b * CAP;
    unsigned long long e0 = cb[t], e1 = cb[t + 1024], e2 = cb[t + 2048], e3 = cb[t + 3072];
    for (int k = 1024; k <= 4096; k <<= 1) {
        s[t] = e0; s[t + 1024] = e1; s[t + 2048] = e2; s[t + 3072] = e3;
        __syncthreads();
        for (int j = k >> 1; j >= 64; j >>= 1) {
            #pragma unroll
            for (int cc = 0; cc < 2; cc++) {
                int c = t + cc * 1024;
                int i = ((c & ~(j - 1)) << 1) | (c & (j - 1));
                int l = i + j;
                bool desc = ((i & k) == 0);
                unsigned long long x = s[i], y = s[l];
                if (desc ? (x < y) : (x > y)) { s[i] = y; s[l] = x; }
            }
            __syncthreads();
        }
        e0 = s[t]; e1 = s[t + 1024]; e2 = s[t + 2048]; e3 = s[t + 3072];
        bool d0 = ((t & k) == 0);
        bool d1 = (((t + 1024) & k) == 0);
        bool d2 = (((t + 2048) & k) == 0);
        bool d3 = (((t + 3072) & k) == 0);
        #pragma unroll
        for (int j = 32; j >= 1; j >>= 1) {
            bool lo = ((t & j) == 0);
            unsigned long long p0 = __shfl_xor(e0, j, 64);
            unsigned long long p1 = __shfl_xor(e1, j, 64);
            unsigned long long p2 = __shfl_xor(e2, j, 64);
            unsigned long long p3 = __shfl_xor(e3, j, 64);
            e0 = REGX(e0, p0, d0, lo);
            e1 = REGX(e1, p1, d1, lo);
            e2 = REGX(e2, p2, d2, lo);
            e3 = REGX(e3, p3, d3, lo);
        }
    }
    float W = (float)*Wp, H = (float)*Hp;
    #pragma unroll
    for (int m = 0; m < 2; m++) {
        unsigned long long v = m ? e1 : e0;
        int r = t + m * 1024;
        unsigned key = (unsigned)(v >> 32);
        bool valid = key > 0x007FFFFFu;
        float4 outb = {0.f, 0.f, 0.f, 0.f};
        if (valid) {
            unsigned idx = ~((unsigned)v);
            float4 a = ((const float4*)anch)[idx];
            float4 d = ((const float4*)pred)[(size_t)b * N + idx];
            outb = decode_box(a, d, W, H);
        }
        topbox[(size_t)b * NP2 + r] = outb;
        if (r < TOPN && !valid) atomicOr(&remInit[b * 64 + (r >> 5)], 1u << (r & 31));
    }
}

// K5: suppression bitmask: mask[i][w] bit jj = (j>i) && iou(i,j)>0.7, j=w*32+jj
__global__ void k_mask(const float4* __restrict__ topbox, unsigned* __restrict__ mask) {
    __shared__ float4 bx[NP2];
    int b = blockIdx.y;
    int t = threadIdx.y * 64 + threadIdx.x;
    for (int i = t; i < NP2; i += 256) bx[i] = topbox[(size_t)b * NP2 + i];
    __syncthreads();
    int i = blockIdx.x * 4 + threadIdx.y;   // 0..1999
    int w = threadIdx.x;                    // 0..63
    float4 bi = bx[i];
    float areai = (bi.z - bi.x) * (bi.w - bi.y);
    unsigned bits = 0;
    int jbase = w * 32;
    #pragma unroll 8
    for (int jj = 0; jj < 32; jj++) {
        int j = jbase + jj;
        if (j > i) {
            float4 bj = bx[j];
            float iw = fmaxf(fminf(bi.z, bj.z) - fmaxf(bi.x, bj.x), 0.0f);
            float ih = fmaxf(fminf(bi.w, bj.w) - fmaxf(bi.y, bj.y), 0.0f);
            float inter = iw * ih;
            float areaj = (bj.z - bj.x) * (bj.w - bj.y);
            float iou = inter / (areai + areaj - inter + 1e-9f);
            if (iou > 0.7f) bits |= (1u << jj);
        }
    }
    mask[((size_t)b * NP2 + i) * 64 + w] = bits;
}

// K6: LDS-staged chunked serial NMS. 1 block/image, 8 waves; wave 0 resolves.
// Per chunk: 32 coalesced ds_read_b32 -> R[32] VGPRs (double-buffered across
// chunks); intra words + removal word via v_readlane (SGPR); serial chain is
// pure SALU; apply is cndmask/or trees. Nothing memory-latent in the chain.
__global__ void __launch_bounds__(512, 2) k_nms(const unsigned* __restrict__ mask,
        const unsigned* __restrict__ remInit, const float4* __restrict__ topbox,
        float* __restrict__ out, int B) {
    __shared__ __align__(16) unsigned sm[2][SROWS * 64];   // 64 KB
    int b = blockIdx.x;
    int t = threadIdx.x;
    const unsigned* m = mask + (size_t)b * NP2 * 64;

    float4* ob = (float4*)out + (size_t)b * OUTN;
    for (int i = t; i < OUTN; i += 512) ob[i] = make_float4(0.f, 0.f, 0.f, 0.f);
    float* vout = out + (size_t)B * (OUTN * 4) + (size_t)b * OUTN;
    for (int i = t; i < OUTN; i += 512) vout[i] = 0.0f;

    {
        const uint4* src = (const uint4*)m;
        uint4* dst = (uint4*)sm[0];
        for (int i = t; i < SROWS * 16; i += 512) dst[i] = src[i];
    }
    __syncthreads();

    unsigned removed = 0xFFFFFFFFu;
    if (t < 64) {
        removed = remInit[b * 64 + t];
        if (t == 62) removed |= 0xFFFF0000u;   // ranks 2000..2015
        if (t == 63) removed = 0xFFFFFFFFu;    // ranks 2016..2047
    }

#define LOADR(R, buf, cl) do {                                                \
        const unsigned* rowb_ = (buf) + (cl) * 32 * 64;                       \
        _Pragma("unroll") for (int jj = 0; jj < 32; jj++)                     \
            R[jj] = rowb_[jj * 64 + t];                                       \
    } while (0)

#define RESOLVE(R, c) do {                                                    \
        unsigned alive = ~__builtin_amdgcn_readlane(removed, (c));            \
        unsigned Is[32];                                                      \
        _Pragma("unroll") for (int jj = 0; jj < 32; jj++)                     \
            Is[jj] = __builtin_amdgcn_readlane(R[jj], (c));                   \
        _Pragma("unroll") for (int jj = 0; jj < 32; jj++)                     \
            alive &= ~(((alive >> jj) & 1u) ? Is[jj] : 0u);                   \
        unsigned a0 = 0, a1 = 0, a2 = 0, a3 = 0;                              \
        _Pragma("unroll") for (int jj = 0; jj < 32; jj += 4) {                \
            a0 |= ((alive >> jj) & 1u)       ? R[jj]     : 0u;                \
            a1 |= ((alive >> (jj + 1)) & 1u) ? R[jj + 1] : 0u;                \
            a2 |= ((alive >> (jj + 2)) & 1u) ? R[jj + 2] : 0u;                \
            a3 |= ((alive >> (jj + 3)) & 1u) ? R[jj + 3] : 0u;                \
        }                                                                     \
        removed |= (a0 | a1) | (a2 | a3);                                     \
    } while (0)

    const int NS = NP2 / SROWS;   // 16 stages
    for (int s = 0; s < NS; s++) {
        if (s + 1 < NS && t >= 64) {
            const uint4* src = (const uint4*)(m + (size_t)(s + 1) * SROWS * 64);
            uint4* dst = (uint4*)sm[(s + 1) & 1];
            for (int i = t - 64; i < SROWS * 16; i += 448) dst[i] = src[i];
        }
        if (t < 64) {
            const unsigned* buf = sm[s & 1];
            int c0 = s * SCH;
            unsigned RA[32], RB[32];
            LOADR(RA, buf, 0);
            LOADR(RB, buf, 1);
            RESOLVE(RA, c0);
            LOADR(RA, buf, 2);
            RESOLVE(RB, c0 + 1);
            LOADR(RB, buf, 3);
            RESOLVE(RA, c0 + 2);
            if (c0 + 3 < 63) RESOLVE(RB, c0 + 3);
        }
        __syncthreads();
    }
#undef LOADR
#undef RESOLVE

    if (t < 64) {
        unsigned keep = ~removed;
        int cnt = __popc(keep);
        int ex = cnt;
        for (int off = 1; off < 64; off <<= 1) {
            int v = __shfl_up(ex, off, 64);
            if (t >= off) ex += v;
        }
        ex -= cnt;
        int pos = ex;
        for (int j = 0; j < 32; j++) {
            if ((keep >> j) & 1u) {
                if (pos < OUTN) {
                    float4 bxv = topbox[(size_t)b * NP2 + t * 32 + j];
                    ob[pos] = bxv;
                    vout[pos] = 1.0f;
                }
                pos++;
            }
        }
    }
}

extern "C" void kernel_launch(void* const* d_in, const int* in_sizes, int n_in,
                              void* d_out, int out_size, void* d_ws, size_t ws_size,
                              hipStream_t stream) {
    const float* pred = (const float*)d_in[0];
    const float* obj  = (const float*)d_in[1];
    const float* anch = (const float*)d_in[2];
    const int* Hp = (const int*)d_in[3];
    const int* Wp = (const int*)d_in[4];
    int N = in_sizes[2] / 4;           // 250000
    int B = in_sizes[1] / N;           // 8

    char* ws = (char*)d_ws;
    size_t off = 0;
    auto take = [&](size_t bytes) { void* p = ws + off; off = (off + bytes + 255) & ~(size_t)255; return p; };

    // Region A: keys (k_pass1..k_collect), reused as mask (k_mask..k_nms)
    size_t regA_bytes = (size_t)B * N * 4;                       // 8.0 MB
    size_t mask_bytes = (size_t)B * NP2 * 64 * 4;                // 4.2 MB (< regA)
    char* regA = (char*)take(regA_bytes > mask_bytes ? regA_bytes : mask_bytes);
    unsigned* keys = (unsigned*)regA;
    unsigned* mask = (unsigned*)regA;
    unsigned* hist           = (unsigned*)take((size_t)B * NBUCK * 4);   // 256 KB
    unsigned long long* cand = (unsigned long long*)take((size_t)B * CAP * 8);
    float4* topbox           = (float4*)take((size_t)B * NP2 * 16);
    unsigned* cnt            = (unsigned*)take((size_t)B * 64 * 4);
    unsigned* Lb             = (unsigned*)take((size_t)B * 64 * 4);
    unsigned* remInit        = (unsigned*)take((size_t)B * 64 * 4);

    hipMemsetAsync(hist, 0, (size_t)B * NBUCK * 4, stream);

    k_pass1  <<<dim3(P1B, B), 1024, 0, stream>>>(pred, obj, anch, Hp, Wp, keys, hist, cnt, remInit, N);
    k_scan   <<<B, 256, 0, stream>>>(hist, Lb);
    k_collect<<<dim3((N + 1023) / 1024, B), 256, 0, stream>>>(keys, Lb, cnt, cand, N);
    k_sort1  <<<B * 8, 256, 0, stream>>>(cand, cnt);
    k_sort2  <<<B, 1024, 0, stream>>>(cand, pred, anch, Hp, Wp, topbox, remInit, N);
    k_mask   <<<dim3(TOPN / 4, B), dim3(64, 4), 0, stream>>>(topbox, mask);
    k_nms    <<<B, 512, 0, stream>>>(mask, remInit, topbox, (float*)d_out, B);
}